// Round 1
// baseline (2939.507 us; speedup 1.0000x reference)
//
#include <hip/hip_runtime.h>
#include <hip/hip_bf16.h>
#include <cstdint>
#include <cstddef>

#define NN 50000
#define NE 800000

// ---------------------------------------------------------------------------
// count_kernel: cnt[n] = number of edges with receiver n (fp32)
// ---------------------------------------------------------------------------
__global__ void count_kernel(const int* __restrict__ receivers, float* __restrict__ cnt) {
    int e = blockIdx.x * blockDim.x + threadIdx.x;
    if (e < NE) atomicAdd(cnt + receivers[e], 1.0f);
}

// ---------------------------------------------------------------------------
// edge_mlp_kernel: per 64-edge tile:
//   msg = relu(relu(concat(x[recv], x[send]) @ W1 + b1) @ W2 + b2)   [64 x 128]
//   atomicAdd into seg_sum[recv]
// Block = 256 threads (16x16 thread grid), fp32, LDS-tiled GEMMs.
// ---------------------------------------------------------------------------
__global__ __launch_bounds__(256) void edge_mlp_kernel(
    const float* __restrict__ x,        // [NN, 128]
    const int*   __restrict__ senders,
    const int*   __restrict__ receivers,
    const float* __restrict__ W1,       // [256, 64]
    const float* __restrict__ b1,       // [64]
    const float* __restrict__ W2,       // [64, 128]
    const float* __restrict__ b2,       // [128]
    float*       __restrict__ seg_sum)  // [NN, 128] pre-zeroed
{
    __shared__ int   sRecv[64];
    __shared__ int   sSend[64];
    __shared__ float sb1[64];
    __shared__ float sb2[128];
    // phase-unioned scratch: phase1 = sA[64][68] + sB[64][68]
    //                        phase2 = sH[64][68] + sW2[64][132]
    __shared__ float smem[64*68 + 64*132];
    float* sA = smem;           // A-tile / h-tile, row stride 68 (pad vs bank conflicts)
    float* sB = smem + 64*68;   // W1 chunk / W2, row stride 68 / 132

    const int t  = threadIdx.x;
    const int tr = t >> 4;      // 0..15 -> edge group (4 edges each)
    const int tc = t & 15;      // 0..15 -> output-col group
    const int e0 = blockIdx.x * 64;

    if (t < 64) {
        sRecv[t] = receivers[e0 + t];
        sSend[t] = senders[e0 + t];
        sb1[t]   = b1[t];
    }
    if (t < 128) sb2[t] = b2[t];
    __syncthreads();

    // ---------------- GEMM 1: [64e x 256] @ [256 x 64] -> c1[4][4] ----------
    float c1[4][4] = {};

    for (int k0 = 0; k0 < 256; k0 += 64) {
        const bool userecv = (k0 < 128);          // concat: first 128 = receivers
        const int  colbase = k0 & 127;
        // stage A-tile: 64 rows(e) x 64 cols(k), coalesced float4 gathers
        #pragma unroll
        for (int i = 0; i < 4; ++i) {
            int flat4 = i*256 + t;
            int e  = flat4 >> 4;
            int k4 = (flat4 & 15) << 2;
            int node = userecv ? sRecv[e] : sSend[e];
            float4 v = *(const float4*)(x + (size_t)node*128 + colbase + k4);
            *(float4*)(sA + e*68 + k4) = v;
        }
        // stage W1 chunk: rows k0..k0+63
        #pragma unroll
        for (int i = 0; i < 4; ++i) {
            int flat4 = i*256 + t;
            int kk = flat4 >> 4;
            int c4 = (flat4 & 15) << 2;
            float4 v = *(const float4*)(W1 + (size_t)(k0 + kk)*64 + c4);
            *(float4*)(sB + kk*68 + c4) = v;
        }
        __syncthreads();

        #pragma unroll 4
        for (int kk = 0; kk < 64; ++kk) {
            float a0 = sA[(4*tr+0)*68 + kk];
            float a1 = sA[(4*tr+1)*68 + kk];
            float a2 = sA[(4*tr+2)*68 + kk];
            float a3 = sA[(4*tr+3)*68 + kk];
            float4 b = *(const float4*)(sB + kk*68 + 4*tc);
            c1[0][0] = fmaf(a0, b.x, c1[0][0]); c1[0][1] = fmaf(a0, b.y, c1[0][1]);
            c1[0][2] = fmaf(a0, b.z, c1[0][2]); c1[0][3] = fmaf(a0, b.w, c1[0][3]);
            c1[1][0] = fmaf(a1, b.x, c1[1][0]); c1[1][1] = fmaf(a1, b.y, c1[1][1]);
            c1[1][2] = fmaf(a1, b.z, c1[1][2]); c1[1][3] = fmaf(a1, b.w, c1[1][3]);
            c1[2][0] = fmaf(a2, b.x, c1[2][0]); c1[2][1] = fmaf(a2, b.y, c1[2][1]);
            c1[2][2] = fmaf(a2, b.z, c1[2][2]); c1[2][3] = fmaf(a2, b.w, c1[2][3]);
            c1[3][0] = fmaf(a3, b.x, c1[3][0]); c1[3][1] = fmaf(a3, b.y, c1[3][1]);
            c1[3][2] = fmaf(a3, b.z, c1[3][2]); c1[3][3] = fmaf(a3, b.w, c1[3][3]);
        }
        __syncthreads();
    }

    // ---------------- phase 2: h = relu(c1 + b1) -> LDS; stage W2 ----------
    #pragma unroll
    for (int i = 0; i < 4; ++i) {
        float4 h;
        h.x = fmaxf(c1[i][0] + sb1[4*tc+0], 0.f);
        h.y = fmaxf(c1[i][1] + sb1[4*tc+1], 0.f);
        h.z = fmaxf(c1[i][2] + sb1[4*tc+2], 0.f);
        h.w = fmaxf(c1[i][3] + sb1[4*tc+3], 0.f);
        *(float4*)(sA + (4*tr+i)*68 + 4*tc) = h;
    }
    #pragma unroll
    for (int i = 0; i < 8; ++i) {
        int flat4 = i*256 + t;
        int hk = flat4 >> 5;
        int c4 = (flat4 & 31) << 2;
        float4 v = *(const float4*)(W2 + (size_t)hk*128 + c4);
        *(float4*)(sB + hk*132 + c4) = v;
    }
    __syncthreads();

    // ---------------- GEMM 2: [64e x 64] @ [64 x 128] -> c2[4][8] ----------
    // cols: j<4 -> 4*tc+j ; j>=4 -> 64 + 4*tc + (j-4)
    float c2[4][8] = {};
    #pragma unroll 4
    for (int kk = 0; kk < 64; ++kk) {
        float a0 = sA[(4*tr+0)*68 + kk];
        float a1 = sA[(4*tr+1)*68 + kk];
        float a2 = sA[(4*tr+2)*68 + kk];
        float a3 = sA[(4*tr+3)*68 + kk];
        float4 w0 = *(const float4*)(sB + kk*132 + 4*tc);
        float4 w1 = *(const float4*)(sB + kk*132 + 64 + 4*tc);
        c2[0][0] = fmaf(a0, w0.x, c2[0][0]); c2[0][1] = fmaf(a0, w0.y, c2[0][1]);
        c2[0][2] = fmaf(a0, w0.z, c2[0][2]); c2[0][3] = fmaf(a0, w0.w, c2[0][3]);
        c2[0][4] = fmaf(a0, w1.x, c2[0][4]); c2[0][5] = fmaf(a0, w1.y, c2[0][5]);
        c2[0][6] = fmaf(a0, w1.z, c2[0][6]); c2[0][7] = fmaf(a0, w1.w, c2[0][7]);
        c2[1][0] = fmaf(a1, w0.x, c2[1][0]); c2[1][1] = fmaf(a1, w0.y, c2[1][1]);
        c2[1][2] = fmaf(a1, w0.z, c2[1][2]); c2[1][3] = fmaf(a1, w0.w, c2[1][3]);
        c2[1][4] = fmaf(a1, w1.x, c2[1][4]); c2[1][5] = fmaf(a1, w1.y, c2[1][5]);
        c2[1][6] = fmaf(a1, w1.z, c2[1][6]); c2[1][7] = fmaf(a1, w1.w, c2[1][7]);
        c2[2][0] = fmaf(a2, w0.x, c2[2][0]); c2[2][1] = fmaf(a2, w0.y, c2[2][1]);
        c2[2][2] = fmaf(a2, w0.z, c2[2][2]); c2[2][3] = fmaf(a2, w0.w, c2[2][3]);
        c2[2][4] = fmaf(a2, w1.x, c2[2][4]); c2[2][5] = fmaf(a2, w1.y, c2[2][5]);
        c2[2][6] = fmaf(a2, w1.z, c2[2][6]); c2[2][7] = fmaf(a2, w1.w, c2[2][7]);
        c2[3][0] = fmaf(a3, w0.x, c2[3][0]); c2[3][1] = fmaf(a3, w0.y, c2[3][1]);
        c2[3][2] = fmaf(a3, w0.z, c2[3][2]); c2[3][3] = fmaf(a3, w0.w, c2[3][3]);
        c2[3][4] = fmaf(a3, w1.x, c2[3][4]); c2[3][5] = fmaf(a3, w1.y, c2[3][5]);
        c2[3][6] = fmaf(a3, w1.z, c2[3][6]); c2[3][7] = fmaf(a3, w1.w, c2[3][7]);
    }

    // ---------------- epilogue: relu + bias, atomic scatter -----------------
    #pragma unroll
    for (int i = 0; i < 4; ++i) {
        int node = sRecv[4*tr + i];
        float* dst = seg_sum + (size_t)node * 128;
        #pragma unroll
        for (int j = 0; j < 4; ++j) {
            int colA = 4*tc + j;
            int colB = 64 + 4*tc + j;
            float vA = fmaxf(c2[i][j]     + sb2[colA], 0.f);
            float vB = fmaxf(c2[i][j + 4] + sb2[colB], 0.f);
            atomicAdd(dst + colA, vA);
            atomicAdd(dst + colB, vB);
        }
    }
}

// ---------------------------------------------------------------------------
// node_mean_kernel: h1 = (cnt>0) ? seg/cnt : 0 ; re-zero seg for next layer
// ---------------------------------------------------------------------------
__global__ void node_mean_kernel(float* __restrict__ seg, const float* __restrict__ cnt,
                                 float* __restrict__ h1) {
    int idx = blockIdx.x * blockDim.x + threadIdx.x;  // float4 index
    if (idx >= NN * 32) return;
    int n = idx >> 5;
    float c = cnt[n];
    float inv = (c > 0.f) ? 1.0f / c : 0.f;
    float4 v = ((const float4*)seg)[idx];
    float4 o;
    o.x = v.x * inv; o.y = v.y * inv; o.z = v.z * inv; o.w = v.w * inv;
    ((float4*)h1)[idx] = o;
    ((float4*)seg)[idx] = make_float4(0.f, 0.f, 0.f, 0.f);
}

// ---------------------------------------------------------------------------
// node_tail_kernel: h2 = mean; t = relu(h2 @ Wd1 + bd1); out = t @ Wd2 + bd2
// one wave per node
// ---------------------------------------------------------------------------
__global__ __launch_bounds__(256) void node_tail_kernel(
    const float* __restrict__ seg, const float* __restrict__ cnt,
    const float* __restrict__ Wd1, const float* __restrict__ bd1,
    const float* __restrict__ Wd2, const float* __restrict__ bd2,
    float* __restrict__ out)
{
    __shared__ float sH[4][128];
    const int w = threadIdx.x >> 6;
    const int lane = threadIdx.x & 63;
    const int n = blockIdx.x * 4 + w;
    if (n >= NN) return;
    float c = cnt[n];
    float inv = (c > 0.f) ? 1.0f / c : 0.f;
    sH[w][lane]      = seg[(size_t)n*128 + lane]      * inv;
    sH[w][64 + lane] = seg[(size_t)n*128 + 64 + lane] * inv;
    float acc = bd1[lane];
    #pragma unroll 8
    for (int k = 0; k < 128; ++k)
        acc = fmaf(sH[w][k], Wd1[(size_t)k*64 + lane], acc);
    float p = fmaxf(acc, 0.f) * Wd2[lane];
    #pragma unroll
    for (int off = 32; off > 0; off >>= 1)
        p += __shfl_down(p, off);
    if (lane == 0) out[n] = p + bd2[0];
}

// ---------------------------------------------------------------------------
extern "C" void kernel_launch(void* const* d_in, const int* in_sizes, int n_in,
                              void* d_out, int out_size, void* d_ws, size_t ws_size,
                              hipStream_t stream) {
    const float* x   = (const float*)d_in[0];
    const int*   snd = (const int*)  d_in[1];
    const int*   rcv = (const int*)  d_in[2];
    const float* W1a = (const float*)d_in[3];
    const float* b1a = (const float*)d_in[4];
    const float* W2a = (const float*)d_in[5];
    const float* b2a = (const float*)d_in[6];
    const float* W1b = (const float*)d_in[7];
    const float* b1b = (const float*)d_in[8];
    const float* W2b = (const float*)d_in[9];
    const float* b2b = (const float*)d_in[10];
    const float* Wd1 = (const float*)d_in[11];
    const float* bd1 = (const float*)d_in[12];
    const float* Wd2 = (const float*)d_in[13];
    const float* bd2 = (const float*)d_in[14];
    float* out = (float*)d_out;

    // workspace layout: seg_sum [NN*128] | cnt [NN] | h1 [NN*128]
    float* seg = (float*)d_ws;
    float* cnt = seg + (size_t)NN * 128;
    float* h1  = cnt + NN;

    hipMemsetAsync(seg, 0, (size_t)(NN * 128 + NN) * sizeof(float), stream);

    hipLaunchKernelGGL(count_kernel, dim3((NE + 255) / 256), dim3(256), 0, stream, rcv, cnt);

    hipLaunchKernelGGL(edge_mlp_kernel, dim3(NE / 64), dim3(256), 0, stream,
                       x, snd, rcv, W1a, b1a, W2a, b2a, seg);
    hipLaunchKernelGGL(node_mean_kernel, dim3(NN * 32 / 256), dim3(256), 0, stream,
                       seg, cnt, h1);
    hipLaunchKernelGGL(edge_mlp_kernel, dim3(NE / 64), dim3(256), 0, stream,
                       h1, snd, rcv, W1b, b1b, W2b, b2b, seg);
    hipLaunchKernelGGL(node_tail_kernel, dim3(NN / 4), dim3(256), 0, stream,
                       seg, cnt, Wd1, bd1, Wd2, bd2, out);
}

// Round 2
// 1337.496 us; speedup vs baseline: 2.1978x; 2.1978x over previous
//
#include <hip/hip_runtime.h>
#include <hip/hip_bf16.h>
#include <cstdint>
#include <cstddef>

#define NN 50000
#define NE 800000

typedef __bf16 bf16x8 __attribute__((ext_vector_type(8)));
typedef float  f32x4  __attribute__((ext_vector_type(4)));

// Pre-split, pre-transposed weights (hi/lo bf16 decomposition of fp32).
// W1t layout: [n][k] n<64, k<256 ; W2t layout: [n][k] n<128, k<64.
__device__ __bf16 g_w1h[2][64 * 256];
__device__ __bf16 g_w1l[2][64 * 256];
__device__ __bf16 g_w2h[2][128 * 64];
__device__ __bf16 g_w2l[2][128 * 64];

__device__ __forceinline__ void split1(float v, __bf16& h, __bf16& l) {
    h = (__bf16)v;
    l = (__bf16)(v - (float)h);
}

// ---------------------------------------------------------------------------
// split_w_kernel: fp32 W -> (hi,lo) bf16, transposed, into device globals
// ---------------------------------------------------------------------------
__global__ void split_w_kernel(const float* __restrict__ W1a, const float* __restrict__ W2a,
                               const float* __restrict__ W1b, const float* __restrict__ W2b) {
    int tid = blockIdx.x * blockDim.x + threadIdx.x;
    if (tid < 16384) {                 // W1a [256][64] -> [64][256]
        int k = tid >> 6, n = tid & 63;
        __bf16 h, l; split1(W1a[tid], h, l);
        g_w1h[0][n * 256 + k] = h; g_w1l[0][n * 256 + k] = l;
    } else if (tid < 24576) {          // W2a [64][128] -> [128][64]
        int i = tid - 16384; int k = i >> 7, n = i & 127;
        __bf16 h, l; split1(W2a[i], h, l);
        g_w2h[0][n * 64 + k] = h; g_w2l[0][n * 64 + k] = l;
    } else if (tid < 40960) {          // W1b
        int i = tid - 24576; int k = i >> 6, n = i & 63;
        __bf16 h, l; split1(W1b[i], h, l);
        g_w1h[1][n * 256 + k] = h; g_w1l[1][n * 256 + k] = l;
    } else if (tid < 49152) {          // W2b
        int i = tid - 40960; int k = i >> 7, n = i & 127;
        __bf16 h, l; split1(W2b[i], h, l);
        g_w2h[1][n * 64 + k] = h; g_w2l[1][n * 64 + k] = l;
    }
}

// ---------------------------------------------------------------------------
// count_kernel: cnt[n] = #edges with receiver n (fp32, exact for counts<2^24)
// ---------------------------------------------------------------------------
__global__ void count_kernel(const int* __restrict__ receivers, float* __restrict__ cnt) {
    int e = blockIdx.x * blockDim.x + threadIdx.x;
    if (e < NE) atomicAdd(cnt + receivers[e], 1.0f);
}

// ---------------------------------------------------------------------------
// edge_mfma_kernel: 128 edges/block, 4 waves, each wave owns two 16-edge
// strips. Split-bf16 MFMA for both GEMMs; operands direct from global (L2-hot
// weights), LDS only for the h C-layout -> A-layout transpose.
//   MFMA layouts (m89/m91-verified): A[m=lane&15][k=quad*8+j],
//   B^T rows likewise, C: col=lane&15, row=quad*4+reg.
// ---------------------------------------------------------------------------
__global__ __launch_bounds__(256) void edge_mfma_kernel(
    const float* __restrict__ xf,                          // layer0 fp32 input
    const __bf16* __restrict__ xh, const __bf16* __restrict__ xl,  // layer1 input
    const int* __restrict__ senders, const int* __restrict__ receivers,
    const float* __restrict__ b1, const float* __restrict__ b2,
    float* __restrict__ seg, int layer)
{
    // packed h: low16 = hi bf16 bits, high16 = lo bf16 bits; row stride 72 u32
    __shared__ uint32_t sPack[8][16 * 72];

    const int t = threadIdx.x;
    const int w = t >> 6, lane = t & 63;
    const int quad = lane >> 4, l16 = lane & 15;
    const int e0 = blockIdx.x * 128;

    int recvA[2], sendA[2], recvC[2][4], sbase[2];
    #pragma unroll
    for (int mi = 0; mi < 2; ++mi) {
        sbase[mi] = e0 + 16 * (w + 4 * mi);
        int eA = sbase[mi] + l16;
        recvA[mi] = receivers[eA];
        sendA[mi] = senders[eA];
        #pragma unroll
        for (int r = 0; r < 4; ++r)
            recvC[mi][r] = receivers[sbase[mi] + quad * 4 + r];
    }

    const __bf16* w1h = g_w1h[layer];
    const __bf16* w1l = g_w1l[layer];
    const __bf16* w2h = g_w2h[layer];
    const __bf16* w2l = g_w2l[layer];

    // ---------------- GEMM1: [16x256] @ [256x64] per strip ------------------
    f32x4 acc1[2][4] = {};
    #pragma unroll
    for (int q = 0; q < 8; ++q) {
        const int feat0 = (q & 3) * 32 + quad * 8;
        bf16x8 ah[2], al[2];
        #pragma unroll
        for (int mi = 0; mi < 2; ++mi) {
            const int node = (q < 4) ? recvA[mi] : sendA[mi];
            if (layer == 0) {
                const float* p = xf + (size_t)node * 128 + feat0;
                f32x4 f0 = *(const f32x4*)(p);
                f32x4 f1 = *(const f32x4*)(p + 4);
                #pragma unroll
                for (int j = 0; j < 4; ++j) {
                    __bf16 h, l;
                    split1(f0[j], h, l); ah[mi][j] = h;     al[mi][j] = l;
                    split1(f1[j], h, l); ah[mi][4 + j] = h; al[mi][4 + j] = l;
                }
            } else {
                ah[mi] = *(const bf16x8*)(xh + (size_t)node * 128 + feat0);
                al[mi] = *(const bf16x8*)(xl + (size_t)node * 128 + feat0);
            }
        }
        const int k0 = q * 32 + quad * 8;
        #pragma unroll
        for (int ct = 0; ct < 4; ++ct) {
            bf16x8 bh = *(const bf16x8*)(w1h + (16 * ct + l16) * 256 + k0);
            bf16x8 bl = *(const bf16x8*)(w1l + (16 * ct + l16) * 256 + k0);
            #pragma unroll
            for (int mi = 0; mi < 2; ++mi) {
                acc1[mi][ct] = __builtin_amdgcn_mfma_f32_16x16x32_bf16(ah[mi], bh, acc1[mi][ct], 0, 0, 0);
                acc1[mi][ct] = __builtin_amdgcn_mfma_f32_16x16x32_bf16(al[mi], bh, acc1[mi][ct], 0, 0, 0);
                acc1[mi][ct] = __builtin_amdgcn_mfma_f32_16x16x32_bf16(ah[mi], bl, acc1[mi][ct], 0, 0, 0);
            }
        }
    }

    // ---------------- h = relu(acc1+b1): C-layout -> LDS (split-packed) -----
    #pragma unroll
    for (int ct = 0; ct < 4; ++ct) {
        const int n = 16 * ct + l16;
        const float bv = b1[n];
        #pragma unroll
        for (int mi = 0; mi < 2; ++mi) {
            #pragma unroll
            for (int r = 0; r < 4; ++r) {
                const int m = quad * 4 + r;
                float v = fmaxf(acc1[mi][ct][r] + bv, 0.f);
                __bf16 h, l; split1(v, h, l);
                uint32_t pk = (uint32_t)__builtin_bit_cast(unsigned short, h)
                            | ((uint32_t)__builtin_bit_cast(unsigned short, l) << 16);
                sPack[w + 4 * mi][m * 72 + n] = pk;
            }
        }
    }
    // wave-private LDS region: no __syncthreads needed (compiler orders lgkmcnt)

    // ---------------- GEMM2: [16x64] @ [64x128] per strip -------------------
    f32x4 acc2[2][8] = {};
    #pragma unroll
    for (int s = 0; s < 2; ++s) {
        const int k0 = s * 32 + quad * 8;
        bf16x8 a2h[2], a2l[2];
        #pragma unroll
        for (int mi = 0; mi < 2; ++mi) {
            const uint32_t* ap = &sPack[w + 4 * mi][l16 * 72 + k0];
            union { uint4 q4; uint32_t u[4]; } r0, r1;
            r0.q4 = *(const uint4*)(ap);
            r1.q4 = *(const uint4*)(ap + 4);
            union { uint32_t u[4]; bf16x8 v; } ch, cl;
            #pragma unroll
            for (int p = 0; p < 2; ++p) {
                ch.u[p]     = (r0.u[2 * p] & 0xffffu) | (r0.u[2 * p + 1] << 16);
                cl.u[p]     = (r0.u[2 * p] >> 16)     | (r0.u[2 * p + 1] & 0xffff0000u);
                ch.u[2 + p] = (r1.u[2 * p] & 0xffffu) | (r1.u[2 * p + 1] << 16);
                cl.u[2 + p] = (r1.u[2 * p] >> 16)     | (r1.u[2 * p + 1] & 0xffff0000u);
            }
            a2h[mi] = ch.v; a2l[mi] = cl.v;
        }
        #pragma unroll
        for (int ct = 0; ct < 8; ++ct) {
            bf16x8 bh = *(const bf16x8*)(w2h + (16 * ct + l16) * 64 + k0);
            bf16x8 bl = *(const bf16x8*)(w2l + (16 * ct + l16) * 64 + k0);
            #pragma unroll
            for (int mi = 0; mi < 2; ++mi) {
                acc2[mi][ct] = __builtin_amdgcn_mfma_f32_16x16x32_bf16(a2h[mi], bh, acc2[mi][ct], 0, 0, 0);
                acc2[mi][ct] = __builtin_amdgcn_mfma_f32_16x16x32_bf16(a2l[mi], bh, acc2[mi][ct], 0, 0, 0);
                acc2[mi][ct] = __builtin_amdgcn_mfma_f32_16x16x32_bf16(a2h[mi], bl, acc2[mi][ct], 0, 0, 0);
            }
        }
    }

    // ---------------- epilogue: relu(+b2), atomic scatter to seg ------------
    #pragma unroll
    for (int ct = 0; ct < 8; ++ct) {
        const int n = 16 * ct + l16;
        const float bv = b2[n];
        #pragma unroll
        for (int mi = 0; mi < 2; ++mi) {
            #pragma unroll
            for (int r = 0; r < 4; ++r) {
                float v = fmaxf(acc2[mi][ct][r] + bv, 0.f);
                atomicAdd(seg + (size_t)recvC[mi][r] * 128 + n, v);
            }
        }
    }
}

// ---------------------------------------------------------------------------
// mean_split_kernel: h1 = seg/cnt (0 if cnt==0) -> split bf16 hi/lo; rezero seg
// ---------------------------------------------------------------------------
__global__ void mean_split_kernel(float* __restrict__ seg, const float* __restrict__ cnt,
                                  __bf16* __restrict__ hh, __bf16* __restrict__ hl) {
    int idx = blockIdx.x * blockDim.x + threadIdx.x;   // float4 index
    if (idx >= NN * 32) return;
    int n = idx >> 5;
    float c = cnt[n];
    float inv = (c > 0.f) ? 1.0f / c : 0.f;
    f32x4 v = ((const f32x4*)seg)[idx];
    union { __bf16 b[4]; uint2 u2; } H, L;
    #pragma unroll
    for (int j = 0; j < 4; ++j) {
        __bf16 h, l; split1(v[j] * inv, h, l);
        H.b[j] = h; L.b[j] = l;
    }
    *(uint2*)(hh + 4 * (size_t)idx) = H.u2;
    *(uint2*)(hl + 4 * (size_t)idx) = L.u2;
    ((f32x4*)seg)[idx] = (f32x4){0.f, 0.f, 0.f, 0.f};
}

// ---------------------------------------------------------------------------
// node_tail_kernel: out = relu(mean @ Wd1 + bd1) @ Wd2 + bd2 ; one wave/node
// ---------------------------------------------------------------------------
__global__ __launch_bounds__(256) void node_tail_kernel(
    const float* __restrict__ seg, const float* __restrict__ cnt,
    const float* __restrict__ Wd1, const float* __restrict__ bd1,
    const float* __restrict__ Wd2, const float* __restrict__ bd2,
    float* __restrict__ out)
{
    __shared__ float sH[4][128];
    const int w = threadIdx.x >> 6;
    const int lane = threadIdx.x & 63;
    const int n = blockIdx.x * 4 + w;
    if (n >= NN) return;
    float c = cnt[n];
    float inv = (c > 0.f) ? 1.0f / c : 0.f;
    sH[w][lane]      = seg[(size_t)n * 128 + lane]      * inv;
    sH[w][64 + lane] = seg[(size_t)n * 128 + 64 + lane] * inv;
    float acc = bd1[lane];
    #pragma unroll 8
    for (int k = 0; k < 128; ++k)
        acc = fmaf(sH[w][k], Wd1[(size_t)k * 64 + lane], acc);
    float p = fmaxf(acc, 0.f) * Wd2[lane];
    #pragma unroll
    for (int off = 32; off > 0; off >>= 1)
        p += __shfl_down(p, off);
    if (lane == 0) out[n] = p + bd2[0];
}

// ---------------------------------------------------------------------------
extern "C" void kernel_launch(void* const* d_in, const int* in_sizes, int n_in,
                              void* d_out, int out_size, void* d_ws, size_t ws_size,
                              hipStream_t stream) {
    const float* x   = (const float*)d_in[0];
    const int*   snd = (const int*)  d_in[1];
    const int*   rcv = (const int*)  d_in[2];
    const float* W1a = (const float*)d_in[3];
    const float* b1a = (const float*)d_in[4];
    const float* W2a = (const float*)d_in[5];
    const float* b2a = (const float*)d_in[6];
    const float* W1b = (const float*)d_in[7];
    const float* b1b = (const float*)d_in[8];
    const float* W2b = (const float*)d_in[9];
    const float* b2b = (const float*)d_in[10];
    const float* Wd1 = (const float*)d_in[11];
    const float* bd1 = (const float*)d_in[12];
    const float* Wd2 = (const float*)d_in[13];
    const float* bd2 = (const float*)d_in[14];
    float* out = (float*)d_out;

    // ws layout: seg [NN*128 f32] | cnt [NN f32] | h1h [NN*128 bf16] | h1l [NN*128 bf16]
    float*  seg = (float*)d_ws;
    float*  cnt = seg + (size_t)NN * 128;
    __bf16* h1h = (__bf16*)(cnt + NN);
    __bf16* h1l = h1h + (size_t)NN * 128;

    hipMemsetAsync(seg, 0, (size_t)(NN * 128 + NN) * sizeof(float), stream);

    hipLaunchKernelGGL(split_w_kernel, dim3(192), dim3(256), 0, stream, W1a, W2a, W1b, W2b);
    hipLaunchKernelGGL(count_kernel, dim3((NE + 255) / 256), dim3(256), 0, stream, rcv, cnt);

    hipLaunchKernelGGL(edge_mfma_kernel, dim3(NE / 128), dim3(256), 0, stream,
                       x, (const __bf16*)nullptr, (const __bf16*)nullptr,
                       snd, rcv, b1a, b2a, seg, 0);
    hipLaunchKernelGGL(mean_split_kernel, dim3(NN * 32 / 256), dim3(256), 0, stream,
                       seg, cnt, h1h, h1l);
    hipLaunchKernelGGL(edge_mfma_kernel, dim3(NE / 128), dim3(256), 0, stream,
                       (const float*)nullptr, h1h, h1l, snd, rcv, b1b, b2b, seg, 1);
    hipLaunchKernelGGL(node_tail_kernel, dim3(NN / 4), dim3(256), 0, stream,
                       seg, cnt, Wd1, bd1, Wd2, bd2, out);
}

// Round 3
// 1306.804 us; speedup vs baseline: 2.2494x; 1.0235x over previous
//
#include <hip/hip_runtime.h>
#include <hip/hip_bf16.h>
#include <cstdint>
#include <cstddef>

#define NN 50000
#define NE 800000

typedef __bf16 bf16x8 __attribute__((ext_vector_type(8)));
typedef float  f32x4  __attribute__((ext_vector_type(4)));

// Pre-split, pre-transposed weights (hi/lo bf16 decomposition of fp32).
__device__ __bf16 g_w1h[2][64 * 256];
__device__ __bf16 g_w1l[2][64 * 256];
__device__ __bf16 g_w2h[2][128 * 64];
__device__ __bf16 g_w2l[2][128 * 64];

__device__ __forceinline__ void split1(float v, __bf16& h, __bf16& l) {
    h = (__bf16)v;
    l = (__bf16)(v - (float)h);
}

// ---------------------------------------------------------------------------
// split_w_kernel: fp32 W -> (hi,lo) bf16, transposed, into device globals
// ---------------------------------------------------------------------------
__global__ void split_w_kernel(const float* __restrict__ W1a, const float* __restrict__ W2a,
                               const float* __restrict__ W1b, const float* __restrict__ W2b) {
    int tid = blockIdx.x * blockDim.x + threadIdx.x;
    if (tid < 16384) {                 // W1a [256][64] -> [64][256]
        int k = tid >> 6, n = tid & 63;
        __bf16 h, l; split1(W1a[tid], h, l);
        g_w1h[0][n * 256 + k] = h; g_w1l[0][n * 256 + k] = l;
    } else if (tid < 24576) {          // W2a [64][128] -> [128][64]
        int i = tid - 16384; int k = i >> 7, n = i & 127;
        __bf16 h, l; split1(W2a[i], h, l);
        g_w2h[0][n * 64 + k] = h; g_w2l[0][n * 64 + k] = l;
    } else if (tid < 40960) {          // W1b
        int i = tid - 24576; int k = i >> 6, n = i & 63;
        __bf16 h, l; split1(W1b[i], h, l);
        g_w1h[1][n * 256 + k] = h; g_w1l[1][n * 256 + k] = l;
    } else if (tid < 49152) {          // W2b
        int i = tid - 40960; int k = i >> 7, n = i & 127;
        __bf16 h, l; split1(W2b[i], h, l);
        g_w2h[1][n * 64 + k] = h; g_w2l[1][n * 64 + k] = l;
    }
}

// ---------------------------------------------------------------------------
// Counting sort of edges by receiver (receivers shared by both layers).
// ---------------------------------------------------------------------------
__global__ void hist_kernel(const int* __restrict__ rcv, uint32_t* __restrict__ hist) {
    int e = blockIdx.x * blockDim.x + threadIdx.x;
    if (e < NE) atomicAdd(hist + rcv[e], 1u);
}

// per-256-block exclusive scan + block totals
__global__ void scan1_kernel(const uint32_t* __restrict__ hist,
                             uint32_t* __restrict__ pre, uint32_t* __restrict__ bsum) {
    __shared__ uint32_t s[256];
    int t = threadIdx.x;
    int i = blockIdx.x * 256 + t;
    uint32_t v = (i < NN) ? hist[i] : 0u;
    s[t] = v; __syncthreads();
    #pragma unroll
    for (int off = 1; off < 256; off <<= 1) {
        uint32_t tv = (t >= off) ? s[t - off] : 0u;
        __syncthreads();
        s[t] += tv; __syncthreads();
    }
    if (i < NN) pre[i] = s[t] - v;          // exclusive
    if (t == 255) bsum[blockIdx.x] = s[255];
}

// scan block totals (<=256 of them), single block
__global__ void scan2_kernel(uint32_t* __restrict__ bsum, int nb) {
    __shared__ uint32_t s[256];
    int t = threadIdx.x;
    uint32_t v = (t < nb) ? bsum[t] : 0u;
    s[t] = v; __syncthreads();
    #pragma unroll
    for (int off = 1; off < 256; off <<= 1) {
        uint32_t tv = (t >= off) ? s[t - off] : 0u;
        __syncthreads();
        s[t] += tv; __syncthreads();
    }
    if (t < nb) bsum[t] = s[t] - v;         // exclusive
}

__global__ void scan3_kernel(const uint32_t* __restrict__ pre,
                             const uint32_t* __restrict__ bsum,
                             uint32_t* __restrict__ row_off) {
    int i = blockIdx.x * 256 + threadIdx.x;
    if (i < NN) row_off[i] = pre[i] + bsum[blockIdx.x];
    if (i == 0) row_off[NN] = NE;
}

__global__ void rank_scatter_kernel(const int* __restrict__ rcv,
                                    const uint32_t* __restrict__ row_off,
                                    uint32_t* __restrict__ cursor,
                                    uint32_t* __restrict__ perm) {
    int e = blockIdx.x * blockDim.x + threadIdx.x;
    if (e < NE) {
        int r = rcv[e];
        uint32_t k = atomicAdd(cursor + r, 1u);
        perm[row_off[r] + k] = e;
    }
}

// ---------------------------------------------------------------------------
// edge_mfma_kernel: 128 sorted edges/block, 4 waves x 2 strips of 16.
// Split-bf16 MFMA for both GEMMs. Epilogue does in-register run-reduction
// over consecutive equal receivers (sorted) before atomicAdd.
// ---------------------------------------------------------------------------
__global__ __launch_bounds__(256) void edge_mfma_kernel(
    const float* __restrict__ xf,                          // layer0 fp32 input
    const __bf16* __restrict__ xh, const __bf16* __restrict__ xl,  // layer1 input
    const int* __restrict__ senders, const int* __restrict__ receivers,
    const uint32_t* __restrict__ perm,
    const float* __restrict__ b1, const float* __restrict__ b2,
    float* __restrict__ seg, int layer)
{
    // packed h: low16 = hi bf16 bits, high16 = lo bf16 bits; row stride 72 u32
    __shared__ uint32_t sPack[8][16 * 72];

    const int t = threadIdx.x;
    const int w = t >> 6, lane = t & 63;
    const int quad = lane >> 4, l16 = lane & 15;
    const int e0 = blockIdx.x * 128;

    int recvA[2], sendA[2], recvC[2][4];
    #pragma unroll
    for (int mi = 0; mi < 2; ++mi) {
        int p = e0 + 16 * (w + 4 * mi) + l16;      // sorted position
        int e = (int)perm[p];
        recvA[mi] = receivers[e];
        sendA[mi] = senders[e];
        // receiver of row quad*4+r: shuffle from the lane holding that position
        #pragma unroll
        for (int r = 0; r < 4; ++r)
            recvC[mi][r] = __shfl(recvA[mi], quad * 4 + r, 16);
    }

    const __bf16* w1h = g_w1h[layer];
    const __bf16* w1l = g_w1l[layer];
    const __bf16* w2h = g_w2h[layer];
    const __bf16* w2l = g_w2l[layer];

    // ---------------- GEMM1: [16x256] @ [256x64] per strip ------------------
    f32x4 acc1[2][4] = {};
    #pragma unroll
    for (int q = 0; q < 8; ++q) {
        const int feat0 = (q & 3) * 32 + quad * 8;
        bf16x8 ah[2], al[2];
        #pragma unroll
        for (int mi = 0; mi < 2; ++mi) {
            const int node = (q < 4) ? recvA[mi] : sendA[mi];
            if (layer == 0) {
                const float* p = xf + (size_t)node * 128 + feat0;
                f32x4 f0 = *(const f32x4*)(p);
                f32x4 f1 = *(const f32x4*)(p + 4);
                #pragma unroll
                for (int j = 0; j < 4; ++j) {
                    __bf16 h, l;
                    split1(f0[j], h, l); ah[mi][j] = h;     al[mi][j] = l;
                    split1(f1[j], h, l); ah[mi][4 + j] = h; al[mi][4 + j] = l;
                }
            } else {
                ah[mi] = *(const bf16x8*)(xh + (size_t)node * 128 + feat0);
                al[mi] = *(const bf16x8*)(xl + (size_t)node * 128 + feat0);
            }
        }
        const int k0 = q * 32 + quad * 8;
        #pragma unroll
        for (int ct = 0; ct < 4; ++ct) {
            bf16x8 bh = *(const bf16x8*)(w1h + (16 * ct + l16) * 256 + k0);
            bf16x8 bl = *(const bf16x8*)(w1l + (16 * ct + l16) * 256 + k0);
            #pragma unroll
            for (int mi = 0; mi < 2; ++mi) {
                acc1[mi][ct] = __builtin_amdgcn_mfma_f32_16x16x32_bf16(ah[mi], bh, acc1[mi][ct], 0, 0, 0);
                acc1[mi][ct] = __builtin_amdgcn_mfma_f32_16x16x32_bf16(al[mi], bh, acc1[mi][ct], 0, 0, 0);
                acc1[mi][ct] = __builtin_amdgcn_mfma_f32_16x16x32_bf16(ah[mi], bl, acc1[mi][ct], 0, 0, 0);
            }
        }
    }

    // ---------------- h = relu(acc1+b1): C-layout -> LDS (split-packed) -----
    #pragma unroll
    for (int ct = 0; ct < 4; ++ct) {
        const int n = 16 * ct + l16;
        const float bv = b1[n];
        #pragma unroll
        for (int mi = 0; mi < 2; ++mi) {
            #pragma unroll
            for (int r = 0; r < 4; ++r) {
                const int m = quad * 4 + r;
                float v = fmaxf(acc1[mi][ct][r] + bv, 0.f);
                __bf16 h, l; split1(v, h, l);
                uint32_t pk = (uint32_t)__builtin_bit_cast(unsigned short, h)
                            | ((uint32_t)__builtin_bit_cast(unsigned short, l) << 16);
                sPack[w + 4 * mi][m * 72 + n] = pk;
            }
        }
    }
    // wave-private LDS region: no __syncthreads needed

    // ---------------- GEMM2: [16x64] @ [64x128] per strip -------------------
    f32x4 acc2[2][8] = {};
    #pragma unroll
    for (int s = 0; s < 2; ++s) {
        const int k0 = s * 32 + quad * 8;
        bf16x8 a2h[2], a2l[2];
        #pragma unroll
        for (int mi = 0; mi < 2; ++mi) {
            const uint32_t* ap = &sPack[w + 4 * mi][l16 * 72 + k0];
            union { uint4 q4; uint32_t u[4]; } r0, r1;
            r0.q4 = *(const uint4*)(ap);
            r1.q4 = *(const uint4*)(ap + 4);
            union { uint32_t u[4]; bf16x8 v; } ch, cl;
            #pragma unroll
            for (int p = 0; p < 2; ++p) {
                ch.u[p]     = (r0.u[2 * p] & 0xffffu) | (r0.u[2 * p + 1] << 16);
                cl.u[p]     = (r0.u[2 * p] >> 16)     | (r0.u[2 * p + 1] & 0xffff0000u);
                ch.u[2 + p] = (r1.u[2 * p] & 0xffffu) | (r1.u[2 * p + 1] << 16);
                cl.u[2 + p] = (r1.u[2 * p] >> 16)     | (r1.u[2 * p + 1] & 0xffff0000u);
            }
            a2h[mi] = ch.v; a2l[mi] = cl.v;
        }
        #pragma unroll
        for (int ct = 0; ct < 8; ++ct) {
            bf16x8 bh = *(const bf16x8*)(w2h + (16 * ct + l16) * 64 + k0);
            bf16x8 bl = *(const bf16x8*)(w2l + (16 * ct + l16) * 64 + k0);
            #pragma unroll
            for (int mi = 0; mi < 2; ++mi) {
                acc2[mi][ct] = __builtin_amdgcn_mfma_f32_16x16x32_bf16(a2h[mi], bh, acc2[mi][ct], 0, 0, 0);
                acc2[mi][ct] = __builtin_amdgcn_mfma_f32_16x16x32_bf16(a2l[mi], bh, acc2[mi][ct], 0, 0, 0);
                acc2[mi][ct] = __builtin_amdgcn_mfma_f32_16x16x32_bf16(a2h[mi], bl, acc2[mi][ct], 0, 0, 0);
            }
        }
    }

    // -------- epilogue: relu(+b2); run-reduce equal receivers; atomic -------
    #pragma unroll
    for (int ct = 0; ct < 8; ++ct) {
        const int n = 16 * ct + l16;
        const float bv = b2[n];
        #pragma unroll
        for (int mi = 0; mi < 2; ++mi) {
            float v[4];
            #pragma unroll
            for (int r = 0; r < 4; ++r)
                v[r] = fmaxf(acc2[mi][ct][r] + bv, 0.f);
            int prev = recvC[mi][0];
            float s = v[0];
            #pragma unroll
            for (int r = 1; r < 4; ++r) {
                if (recvC[mi][r] == prev) {
                    s += v[r];
                } else {
                    atomicAdd(seg + (size_t)prev * 128 + n, s);
                    prev = recvC[mi][r];
                    s = v[r];
                }
            }
            atomicAdd(seg + (size_t)prev * 128 + n, s);
        }
    }
}

// ---------------------------------------------------------------------------
// mean_split_kernel: h1 = seg/cnt (0 if cnt==0) -> split bf16 hi/lo; rezero seg
// ---------------------------------------------------------------------------
__global__ void mean_split_kernel(float* __restrict__ seg,
                                  const uint32_t* __restrict__ row_off,
                                  __bf16* __restrict__ hh, __bf16* __restrict__ hl) {
    int idx = blockIdx.x * blockDim.x + threadIdx.x;   // float4 index
    if (idx >= NN * 32) return;
    int n = idx >> 5;
    uint32_t c = row_off[n + 1] - row_off[n];
    float inv = (c > 0u) ? 1.0f / (float)c : 0.f;
    f32x4 v = ((const f32x4*)seg)[idx];
    union { __bf16 b[4]; uint2 u2; } H, L;
    #pragma unroll
    for (int j = 0; j < 4; ++j) {
        __bf16 h, l; split1(v[j] * inv, h, l);
        H.b[j] = h; L.b[j] = l;
    }
    *(uint2*)(hh + 4 * (size_t)idx) = H.u2;
    *(uint2*)(hl + 4 * (size_t)idx) = L.u2;
    ((f32x4*)seg)[idx] = (f32x4){0.f, 0.f, 0.f, 0.f};
}

// ---------------------------------------------------------------------------
// node_tail_kernel: out = relu(mean @ Wd1 + bd1) @ Wd2 + bd2 ; one wave/node
// ---------------------------------------------------------------------------
__global__ __launch_bounds__(256) void node_tail_kernel(
    const float* __restrict__ seg, const uint32_t* __restrict__ row_off,
    const float* __restrict__ Wd1, const float* __restrict__ bd1,
    const float* __restrict__ Wd2, const float* __restrict__ bd2,
    float* __restrict__ out)
{
    __shared__ float sH[4][128];
    const int w = threadIdx.x >> 6;
    const int lane = threadIdx.x & 63;
    const int n = blockIdx.x * 4 + w;
    if (n >= NN) return;
    uint32_t c = row_off[n + 1] - row_off[n];
    float inv = (c > 0u) ? 1.0f / (float)c : 0.f;
    sH[w][lane]      = seg[(size_t)n * 128 + lane]      * inv;
    sH[w][64 + lane] = seg[(size_t)n * 128 + 64 + lane] * inv;
    float acc = bd1[lane];
    #pragma unroll 8
    for (int k = 0; k < 128; ++k)
        acc = fmaf(sH[w][k], Wd1[(size_t)k * 64 + lane], acc);
    float p = fmaxf(acc, 0.f) * Wd2[lane];
    #pragma unroll
    for (int off = 32; off > 0; off >>= 1)
        p += __shfl_down(p, off);
    if (lane == 0) out[n] = p + bd2[0];
}

// ---------------------------------------------------------------------------
extern "C" void kernel_launch(void* const* d_in, const int* in_sizes, int n_in,
                              void* d_out, int out_size, void* d_ws, size_t ws_size,
                              hipStream_t stream) {
    const float* x   = (const float*)d_in[0];
    const int*   snd = (const int*)  d_in[1];
    const int*   rcv = (const int*)  d_in[2];
    const float* W1a = (const float*)d_in[3];
    const float* b1a = (const float*)d_in[4];
    const float* W2a = (const float*)d_in[5];
    const float* b2a = (const float*)d_in[6];
    const float* W1b = (const float*)d_in[7];
    const float* b1b = (const float*)d_in[8];
    const float* W2b = (const float*)d_in[9];
    const float* b2b = (const float*)d_in[10];
    const float* Wd1 = (const float*)d_in[11];
    const float* bd1 = (const float*)d_in[12];
    const float* Wd2 = (const float*)d_in[13];
    const float* bd2 = (const float*)d_in[14];
    float* out = (float*)d_out;

    // ws layout (zeroed region first, contiguous single memset):
    // seg [NN*128 f32] | hist [NN u32] | cursor [NN u32] |
    // row_off [NN+1 u32] | pre [NN u32] | bsum [256 u32] | perm [NE u32] |
    // h1h [NN*128 bf16] | h1l [NN*128 bf16]
    float*    seg     = (float*)d_ws;
    uint32_t* hist    = (uint32_t*)(seg + (size_t)NN * 128);
    uint32_t* cursor  = hist + NN;
    uint32_t* row_off = cursor + NN;
    uint32_t* pre     = row_off + (NN + 1);
    uint32_t* bsum    = pre + NN;
    uint32_t* perm    = bsum + 256;
    __bf16*   h1h     = (__bf16*)(perm + NE);
    __bf16*   h1l     = h1h + (size_t)NN * 128;

    // zero seg + hist + cursor in one shot (contiguous)
    hipMemsetAsync(seg, 0, ((size_t)NN * 128 + 2 * NN) * sizeof(float), stream);

    const int nb = (NN + 255) / 256;   // 196 scan blocks

    hipLaunchKernelGGL(split_w_kernel, dim3(192), dim3(256), 0, stream, W1a, W2a, W1b, W2b);
    hipLaunchKernelGGL(hist_kernel, dim3((NE + 255) / 256), dim3(256), 0, stream, rcv, hist);
    hipLaunchKernelGGL(scan1_kernel, dim3(nb), dim3(256), 0, stream, hist, pre, bsum);
    hipLaunchKernelGGL(scan2_kernel, dim3(1), dim3(256), 0, stream, bsum, nb);
    hipLaunchKernelGGL(scan3_kernel, dim3(nb), dim3(256), 0, stream, pre, bsum, row_off);
    hipLaunchKernelGGL(rank_scatter_kernel, dim3((NE + 255) / 256), dim3(256), 0, stream,
                       rcv, row_off, cursor, perm);

    hipLaunchKernelGGL(edge_mfma_kernel, dim3(NE / 128), dim3(256), 0, stream,
                       x, (const __bf16*)nullptr, (const __bf16*)nullptr,
                       snd, rcv, perm, b1a, b2a, seg, 0);
    hipLaunchKernelGGL(mean_split_kernel, dim3(NN * 32 / 256), dim3(256), 0, stream,
                       seg, row_off, h1h, h1l);
    hipLaunchKernelGGL(edge_mfma_kernel, dim3(NE / 128), dim3(256), 0, stream,
                       (const float*)nullptr, h1h, h1l, snd, rcv, perm, b1b, b2b, seg, 1);
    hipLaunchKernelGGL(node_tail_kernel, dim3(NN / 4), dim3(256), 0, stream,
                       seg, row_off, Wd1, bd1, Wd2, bd2, out);
}

// Round 4
// 923.606 us; speedup vs baseline: 3.1826x; 1.4149x over previous
//
#include <hip/hip_runtime.h>
#include <hip/hip_bf16.h>
#include <cstdint>
#include <cstddef>

#define NN 50000
#define NE 800000

typedef __bf16 bf16x8 __attribute__((ext_vector_type(8)));
typedef float  f32x4  __attribute__((ext_vector_type(4)));

// Pre-split, pre-transposed weights (hi/lo bf16 decomposition of fp32).
// W1t: [n][k] n<64,k<256 ; W2t: [n][k] n<128,k<64.
__device__ __bf16 g_w1h[2][64 * 256];
__device__ __bf16 g_w1l[2][64 * 256];
__device__ __bf16 g_w2h[2][128 * 64];
__device__ __bf16 g_w2l[2][128 * 64];

__device__ __forceinline__ void split1(float v, __bf16& h, __bf16& l) {
    h = (__bf16)v;
    l = (__bf16)(v - (float)h);
}

// ---------------------------------------------------------------------------
__global__ void split_w_kernel(const float* __restrict__ W1a, const float* __restrict__ W2a,
                               const float* __restrict__ W1b, const float* __restrict__ W2b) {
    int tid = blockIdx.x * blockDim.x + threadIdx.x;
    if (tid < 16384) {                 // W1a [256][64] -> [64][256]
        int k = tid >> 6, n = tid & 63;
        __bf16 h, l; split1(W1a[tid], h, l);
        g_w1h[0][n * 256 + k] = h; g_w1l[0][n * 256 + k] = l;
    } else if (tid < 24576) {          // W2a [64][128] -> [128][64]
        int i = tid - 16384; int k = i >> 7, n = i & 127;
        __bf16 h, l; split1(W2a[i], h, l);
        g_w2h[0][n * 64 + k] = h; g_w2l[0][n * 64 + k] = l;
    } else if (tid < 40960) {          // W1b
        int i = tid - 24576; int k = i >> 6, n = i & 63;
        __bf16 h, l; split1(W1b[i], h, l);
        g_w1h[1][n * 256 + k] = h; g_w1l[1][n * 256 + k] = l;
    } else if (tid < 49152) {          // W2b
        int i = tid - 40960; int k = i >> 7, n = i & 127;
        __bf16 h, l; split1(W2b[i], h, l);
        g_w2h[1][n * 64 + k] = h; g_w2l[1][n * 64 + k] = l;
    }
}

// ---------------------------------------------------------------------------
// x_split_kernel: fp32 x -> hi/lo bf16 planes (unifies layer-0 with layer-1)
// ---------------------------------------------------------------------------
__global__ void x_split_kernel(const float* __restrict__ xf,
                               __bf16* __restrict__ xh, __bf16* __restrict__ xl) {
    int idx = blockIdx.x * blockDim.x + threadIdx.x;   // f32x4 index
    if (idx >= NN * 32) return;
    f32x4 v = ((const f32x4*)xf)[idx];
    union { __bf16 b[4]; uint2 u2; } H, L;
    #pragma unroll
    for (int j = 0; j < 4; ++j) { __bf16 h, l; split1(v[j], h, l); H.b[j] = h; L.b[j] = l; }
    *(uint2*)(xh + 4 * (size_t)idx) = H.u2;
    *(uint2*)(xl + 4 * (size_t)idx) = L.u2;
}

// ---------------------------------------------------------------------------
// Counting sort of edges by receiver.
// ---------------------------------------------------------------------------
__global__ void hist_kernel(const int* __restrict__ rcv, uint32_t* __restrict__ hist) {
    int e = blockIdx.x * blockDim.x + threadIdx.x;
    if (e < NE) atomicAdd(hist + rcv[e], 1u);
}

__global__ void scan1_kernel(const uint32_t* __restrict__ hist,
                             uint32_t* __restrict__ pre, uint32_t* __restrict__ bsum) {
    __shared__ uint32_t s[256];
    int t = threadIdx.x;
    int i = blockIdx.x * 256 + t;
    uint32_t v = (i < NN) ? hist[i] : 0u;
    s[t] = v; __syncthreads();
    #pragma unroll
    for (int off = 1; off < 256; off <<= 1) {
        uint32_t tv = (t >= off) ? s[t - off] : 0u;
        __syncthreads();
        s[t] += tv; __syncthreads();
    }
    if (i < NN) pre[i] = s[t] - v;
    if (t == 255) bsum[blockIdx.x] = s[255];
}

__global__ void scan2_kernel(uint32_t* __restrict__ bsum, int nb) {
    __shared__ uint32_t s[256];
    int t = threadIdx.x;
    uint32_t v = (t < nb) ? bsum[t] : 0u;
    s[t] = v; __syncthreads();
    #pragma unroll
    for (int off = 1; off < 256; off <<= 1) {
        uint32_t tv = (t >= off) ? s[t - off] : 0u;
        __syncthreads();
        s[t] += tv; __syncthreads();
    }
    if (t < nb) bsum[t] = s[t] - v;
}

__global__ void scan3_kernel(const uint32_t* __restrict__ pre,
                             const uint32_t* __restrict__ bsum,
                             uint32_t* __restrict__ row_off) {
    int i = blockIdx.x * 256 + threadIdx.x;
    if (i < NN) row_off[i] = pre[i] + bsum[blockIdx.x];
    if (i == 0) row_off[NN] = NE;
}

__global__ void rank_scatter_kernel(const int* __restrict__ rcv,
                                    const uint32_t* __restrict__ row_off,
                                    uint32_t* __restrict__ cursor,
                                    uint32_t* __restrict__ perm) {
    int e = blockIdx.x * blockDim.x + threadIdx.x;
    if (e < NE) {
        int r = rcv[e];
        uint32_t k = atomicAdd(cursor + r, 1u);
        perm[row_off[r] + k] = e;
    }
}

// ---------------------------------------------------------------------------
// edge_mfma_kernel: 128 sorted edges/block, 4 waves, column-split:
//   wave w owns h-cols [16w,16w+16) and out-cols [32w,32w+32) for ALL 128
//   edges. A-tile (concat feats, split hi/lo bf16 planes) staged in LDS in
//   four 64-k chunks by all 256 threads; weights streamed as per-lane
//   fragment loads (24 x 16B per wave total). LDS A-planes are reused for
//   the h transpose between the GEMMs.
// MFMA layouts (m89/m91-verified): A[m=l16][k=quad*8+j], B^T rows likewise,
// C: col=l16, row=quad*4+reg.
// ---------------------------------------------------------------------------
__global__ __launch_bounds__(256) void edge_mfma_kernel(
    const __bf16* __restrict__ xh, const __bf16* __restrict__ xl,
    const int* __restrict__ senders, const int* __restrict__ receivers,
    const uint32_t* __restrict__ perm,
    const float* __restrict__ b1, const float* __restrict__ b2,
    float* __restrict__ seg, int layer)
{
    // A-planes: 128 edges x 64 k (per chunk), row stride 72 bf16 (144 B,
    // 16B-aligned, 4-bank rotation -> uniform b128 bank spread).
    __shared__ __align__(16) __bf16 sAh[128 * 72];
    __shared__ __align__(16) __bf16 sAl[128 * 72];
    __shared__ int sRecv[128];
    __shared__ int sSend[128];

    const int t = threadIdx.x;
    const int w = t >> 6, lane = t & 63;
    const int quad = lane >> 4, l16 = lane & 15;
    const int p0 = blockIdx.x * 128;

    if (t < 128) {
        int e = (int)perm[p0 + t];
        sRecv[t] = receivers[e];
        sSend[t] = senders[e];
    }

    const __bf16* w1h = g_w1h[layer];
    const __bf16* w1l = g_w1l[layer];
    const __bf16* w2h = g_w2h[layer];
    const __bf16* w2l = g_w2l[layer];

    const float b1v  = b1[16 * w + l16];
    const float b2v0 = b2[32 * w + l16];
    const float b2v1 = b2[32 * w + 16 + l16];

    __syncthreads();

    const int eS = t >> 1;          // staging edge
    const int hS = t & 1;           // staging half (32 k each)

    // ---------------- GEMM1 over 4 k-chunks ---------------------------------
    f32x4 acc1[8] = {};
    #pragma unroll
    for (int c = 0; c < 4; ++c) {
        // weight fragments for this chunk (independent 16B loads)
        bf16x8 bh1[2], bl1[2];
        #pragma unroll
        for (int qq = 0; qq < 2; ++qq) {
            const int kg = c * 64 + qq * 32 + quad * 8;
            bh1[qq] = *(const bf16x8*)(w1h + (16 * w + l16) * 256 + kg);
            bl1[qq] = *(const bf16x8*)(w1l + (16 * w + l16) * 256 + kg);
        }
        // cooperative staging: 8 independent 16B loads per thread
        {
            const int node  = (c < 2) ? sRecv[eS] : sSend[eS];
            const int fbase = (c & 1) * 64 + hS * 32;
            const __bf16* ph = xh + (size_t)node * 128 + fbase;
            const __bf16* pl = xl + (size_t)node * 128 + fbase;
            bf16x8 vh[4], vl[4];
            #pragma unroll
            for (int v = 0; v < 4; ++v) { vh[v] = *(const bf16x8*)(ph + 8 * v);
                                          vl[v] = *(const bf16x8*)(pl + 8 * v); }
            __bf16* dh = sAh + eS * 72 + hS * 32;
            __bf16* dl = sAl + eS * 72 + hS * 32;
            #pragma unroll
            for (int v = 0; v < 4; ++v) { *(bf16x8*)(dh + 8 * v) = vh[v];
                                          *(bf16x8*)(dl + 8 * v) = vl[v]; }
        }
        __syncthreads();
        // GEMM1 chunk: 8 m-strips x 2 q x 3 mfma
        #pragma unroll
        for (int strip = 0; strip < 8; ++strip) {
            const __bf16* arh = sAh + (16 * strip + l16) * 72;
            const __bf16* arl = sAl + (16 * strip + l16) * 72;
            #pragma unroll
            for (int qq = 0; qq < 2; ++qq) {
                const int kl = qq * 32 + quad * 8;
                bf16x8 ah = *(const bf16x8*)(arh + kl);
                bf16x8 al = *(const bf16x8*)(arl + kl);
                acc1[strip] = __builtin_amdgcn_mfma_f32_16x16x32_bf16(ah, bh1[qq], acc1[strip], 0, 0, 0);
                acc1[strip] = __builtin_amdgcn_mfma_f32_16x16x32_bf16(al, bh1[qq], acc1[strip], 0, 0, 0);
                acc1[strip] = __builtin_amdgcn_mfma_f32_16x16x32_bf16(ah, bl1[qq], acc1[strip], 0, 0, 0);
            }
        }
        __syncthreads();   // chunk consumed before overwrite
    }

    // ---------------- h = relu(acc1+b1) -> planes (alias A buffers) ---------
    #pragma unroll
    for (int strip = 0; strip < 8; ++strip) {
        #pragma unroll
        for (int r = 0; r < 4; ++r) {
            float v = fmaxf(acc1[strip][r] + b1v, 0.f);
            __bf16 hh, hl; split1(v, hh, hl);
            const int e = 16 * strip + quad * 4 + r;
            sAh[e * 72 + 16 * w + l16] = hh;
            sAl[e * 72 + 16 * w + l16] = hl;
        }
    }
    __syncthreads();

    // ---------------- GEMM2: [128x64] @ [64x32-cols-per-wave] ---------------
    f32x4 acc2[8][2] = {};
    #pragma unroll
    for (int s = 0; s < 2; ++s) {
        const int k0 = s * 32 + quad * 8;
        bf16x8 b2h[2], b2l[2];
        #pragma unroll
        for (int c2 = 0; c2 < 2; ++c2) {
            const int n2 = 32 * w + 16 * c2 + l16;
            b2h[c2] = *(const bf16x8*)(w2h + n2 * 64 + k0);
            b2l[c2] = *(const bf16x8*)(w2l + n2 * 64 + k0);
        }
        #pragma unroll
        for (int strip = 0; strip < 8; ++strip) {
            bf16x8 ah = *(const bf16x8*)(sAh + (16 * strip + l16) * 72 + k0);
            bf16x8 al = *(const bf16x8*)(sAl + (16 * strip + l16) * 72 + k0);
            #pragma unroll
            for (int c2 = 0; c2 < 2; ++c2) {
                acc2[strip][c2] = __builtin_amdgcn_mfma_f32_16x16x32_bf16(ah, b2h[c2], acc2[strip][c2], 0, 0, 0);
                acc2[strip][c2] = __builtin_amdgcn_mfma_f32_16x16x32_bf16(al, b2h[c2], acc2[strip][c2], 0, 0, 0);
                acc2[strip][c2] = __builtin_amdgcn_mfma_f32_16x16x32_bf16(ah, b2l[c2], acc2[strip][c2], 0, 0, 0);
            }
        }
    }

    // -------- epilogue: relu(+b2); run-reduce equal receivers; atomic -------
    #pragma unroll
    for (int c2 = 0; c2 < 2; ++c2) {
        const int n = 32 * w + 16 * c2 + l16;
        const float bv = c2 ? b2v1 : b2v0;
        #pragma unroll
        for (int strip = 0; strip < 8; ++strip) {
            const int ebase = 16 * strip + quad * 4;
            int rc[4];
            float v[4];
            #pragma unroll
            for (int r = 0; r < 4; ++r) {
                rc[r] = sRecv[ebase + r];
                v[r]  = fmaxf(acc2[strip][c2][r] + bv, 0.f);
            }
            int prev = rc[0];
            float sm = v[0];
            #pragma unroll
            for (int r = 1; r < 4; ++r) {
                if (rc[r] == prev) {
                    sm += v[r];
                } else {
                    atomicAdd(seg + (size_t)prev * 128 + n, sm);
                    prev = rc[r];
                    sm = v[r];
                }
            }
            atomicAdd(seg + (size_t)prev * 128 + n, sm);
        }
    }
}

// ---------------------------------------------------------------------------
// mean_split_kernel: h1 = seg/cnt -> hi/lo planes (reuses x-plane buffers);
// re-zeros seg for layer 2.
// ---------------------------------------------------------------------------
__global__ void mean_split_kernel(float* __restrict__ seg,
                                  const uint32_t* __restrict__ row_off,
                                  __bf16* __restrict__ hh, __bf16* __restrict__ hl) {
    int idx = blockIdx.x * blockDim.x + threadIdx.x;   // f32x4 index
    if (idx >= NN * 32) return;
    int n = idx >> 5;
    uint32_t c = row_off[n + 1] - row_off[n];
    float inv = (c > 0u) ? 1.0f / (float)c : 0.f;
    f32x4 v = ((const f32x4*)seg)[idx];
    union { __bf16 b[4]; uint2 u2; } H, L;
    #pragma unroll
    for (int j = 0; j < 4; ++j) {
        __bf16 h, l; split1(v[j] * inv, h, l);
        H.b[j] = h; L.b[j] = l;
    }
    *(uint2*)(hh + 4 * (size_t)idx) = H.u2;
    *(uint2*)(hl + 4 * (size_t)idx) = L.u2;
    ((f32x4*)seg)[idx] = (f32x4){0.f, 0.f, 0.f, 0.f};
}

// ---------------------------------------------------------------------------
// node_tail_kernel: out = relu(mean @ Wd1 + bd1) @ Wd2 + bd2 ; one wave/node
// ---------------------------------------------------------------------------
__global__ __launch_bounds__(256) void node_tail_kernel(
    const float* __restrict__ seg, const uint32_t* __restrict__ row_off,
    const float* __restrict__ Wd1, const float* __restrict__ bd1,
    const float* __restrict__ Wd2, const float* __restrict__ bd2,
    float* __restrict__ out)
{
    __shared__ float sH[4][128];
    const int w = threadIdx.x >> 6;
    const int lane = threadIdx.x & 63;
    const int n = blockIdx.x * 4 + w;
    if (n >= NN) return;
    uint32_t c = row_off[n + 1] - row_off[n];
    float inv = (c > 0u) ? 1.0f / (float)c : 0.f;
    sH[w][lane]      = seg[(size_t)n * 128 + lane]      * inv;
    sH[w][64 + lane] = seg[(size_t)n * 128 + 64 + lane] * inv;
    float acc = bd1[lane];
    #pragma unroll 8
    for (int k = 0; k < 128; ++k)
        acc = fmaf(sH[w][k], Wd1[(size_t)k * 64 + lane], acc);
    float p = fmaxf(acc, 0.f) * Wd2[lane];
    #pragma unroll
    for (int off = 32; off > 0; off >>= 1)
        p += __shfl_down(p, off);
    if (lane == 0) out[n] = p + bd2[0];
}

// ---------------------------------------------------------------------------
extern "C" void kernel_launch(void* const* d_in, const int* in_sizes, int n_in,
                              void* d_out, int out_size, void* d_ws, size_t ws_size,
                              hipStream_t stream) {
    const float* x   = (const float*)d_in[0];
    const int*   snd = (const int*)  d_in[1];
    const int*   rcv = (const int*)  d_in[2];
    const float* W1a = (const float*)d_in[3];
    const float* b1a = (const float*)d_in[4];
    const float* W2a = (const float*)d_in[5];
    const float* b2a = (const float*)d_in[6];
    const float* W1b = (const float*)d_in[7];
    const float* b1b = (const float*)d_in[8];
    const float* W2b = (const float*)d_in[9];
    const float* b2b = (const float*)d_in[10];
    const float* Wd1 = (const float*)d_in[11];
    const float* bd1 = (const float*)d_in[12];
    const float* Wd2 = (const float*)d_in[13];
    const float* bd2 = (const float*)d_in[14];
    float* out = (float*)d_out;

    // ws layout: seg [NN*128 f32] | hist [NN u32] | cursor [NN u32] |
    // row_off [NN+1] | pre [NN] | bsum [256] | perm [NE] |
    // planes ph/pl [NN*128 bf16 each] (x for layer0, then h1 for layer1)
    float*    seg     = (float*)d_ws;
    uint32_t* hist    = (uint32_t*)(seg + (size_t)NN * 128);
    uint32_t* cursor  = hist + NN;
    uint32_t* row_off = cursor + NN;
    uint32_t* pre     = row_off + (NN + 1);
    uint32_t* bsum    = pre + NN;
    uint32_t* perm    = bsum + 256;
    __bf16*   ph      = (__bf16*)(perm + NE);
    __bf16*   pl      = ph + (size_t)NN * 128;

    hipMemsetAsync(seg, 0, ((size_t)NN * 128 + 2 * NN) * sizeof(float), stream);

    const int nb = (NN + 255) / 256;

    hipLaunchKernelGGL(split_w_kernel, dim3(192), dim3(256), 0, stream, W1a, W2a, W1b, W2b);
    hipLaunchKernelGGL(x_split_kernel, dim3((NN * 32 + 255) / 256), dim3(256), 0, stream,
                       x, ph, pl);
    hipLaunchKernelGGL(hist_kernel, dim3((NE + 255) / 256), dim3(256), 0, stream, rcv, hist);
    hipLaunchKernelGGL(scan1_kernel, dim3(nb), dim3(256), 0, stream, hist, pre, bsum);
    hipLaunchKernelGGL(scan2_kernel, dim3(1), dim3(256), 0, stream, bsum, nb);
    hipLaunchKernelGGL(scan3_kernel, dim3(nb), dim3(256), 0, stream, pre, bsum, row_off);
    hipLaunchKernelGGL(rank_scatter_kernel, dim3((NE + 255) / 256), dim3(256), 0, stream,
                       rcv, row_off, cursor, perm);

    hipLaunchKernelGGL(edge_mfma_kernel, dim3(NE / 128), dim3(256), 0, stream,
                       ph, pl, snd, rcv, perm, b1a, b2a, seg, 0);
    hipLaunchKernelGGL(mean_split_kernel, dim3(NN * 32 / 256), dim3(256), 0, stream,
                       seg, row_off, ph, pl);
    hipLaunchKernelGGL(edge_mfma_kernel, dim3(NE / 128), dim3(256), 0, stream,
                       ph, pl, snd, rcv, perm, b1b, b2b, seg, 1);
    hipLaunchKernelGGL(node_tail_kernel, dim3(NN / 4), dim3(256), 0, stream,
                       seg, row_off, Wd1, bd1, Wd2, bd2, out);
}

// Round 5
// 808.805 us; speedup vs baseline: 3.6344x; 1.1419x over previous
//
#include <hip/hip_runtime.h>
#include <hip/hip_bf16.h>
#include <cstdint>
#include <cstddef>

#define NN 50000
#define NE 800000

typedef __bf16 bf16x8 __attribute__((ext_vector_type(8)));
typedef float  f32x4  __attribute__((ext_vector_type(4)));

// Pre-split, pre-transposed weights (hi/lo bf16 decomposition of fp32).
// W1t: [n][k] n<64,k<256 ; W2t: [n][k] n<128,k<64 ; Wd1t: [n][k] n<64,k<128.
__device__ __bf16 g_w1h[2][64 * 256];
__device__ __bf16 g_w1l[2][64 * 256];
__device__ __bf16 g_w2h[2][128 * 64];
__device__ __bf16 g_w2l[2][128 * 64];
__device__ __bf16 g_wd1h[64 * 128];
__device__ __bf16 g_wd1l[64 * 128];

__device__ __forceinline__ void split1(float v, __bf16& h, __bf16& l) {
    h = (__bf16)v;
    l = (__bf16)(v - (float)h);
}

// pack: low16 = hi bf16 bits, high16 = lo bf16 bits
__device__ __forceinline__ uint32_t pack_split(float v) {
    __bf16 h, l; split1(v, h, l);
    return (uint32_t)__builtin_bit_cast(unsigned short, h)
         | ((uint32_t)__builtin_bit_cast(unsigned short, l) << 16);
}

// 8 packed u32 (k0..k0+7) -> hi-plane and lo-plane bf16x8 A/B fragments
__device__ __forceinline__ void unpack8(uint4 u0, uint4 u1, bf16x8& ah, bf16x8& al) {
    const uint32_t a[8] = {u0.x, u0.y, u0.z, u0.w, u1.x, u1.y, u1.z, u1.w};
    union { uint32_t u[4]; bf16x8 v; } H, L;
    #pragma unroll
    for (int i = 0; i < 4; ++i) {
        H.u[i] = (a[2*i] & 0xffffu) | (a[2*i+1] << 16);
        L.u[i] = (a[2*i] >> 16)     | (a[2*i+1] & 0xffff0000u);
    }
    ah = H.v; al = L.v;
}

// ---------------------------------------------------------------------------
// split_w_kernel: fp32 W -> (hi,lo) bf16, transposed, into device globals
// ---------------------------------------------------------------------------
__global__ void split_w_kernel(const float* __restrict__ W1a, const float* __restrict__ W2a,
                               const float* __restrict__ W1b, const float* __restrict__ W2b,
                               const float* __restrict__ Wd1) {
    int tid = blockIdx.x * blockDim.x + threadIdx.x;
    if (tid < 16384) {                 // W1a [256][64] -> [64][256]
        int k = tid >> 6, n = tid & 63;
        __bf16 h, l; split1(W1a[tid], h, l);
        g_w1h[0][n * 256 + k] = h; g_w1l[0][n * 256 + k] = l;
    } else if (tid < 24576) {          // W2a [64][128] -> [128][64]
        int i = tid - 16384; int k = i >> 7, n = i & 127;
        __bf16 h, l; split1(W2a[i], h, l);
        g_w2h[0][n * 64 + k] = h; g_w2l[0][n * 64 + k] = l;
    } else if (tid < 40960) {          // W1b
        int i = tid - 24576; int k = i >> 6, n = i & 63;
        __bf16 h, l; split1(W1b[i], h, l);
        g_w1h[1][n * 256 + k] = h; g_w1l[1][n * 256 + k] = l;
    } else if (tid < 49152) {          // W2b
        int i = tid - 40960; int k = i >> 7, n = i & 127;
        __bf16 h, l; split1(W2b[i], h, l);
        g_w2h[1][n * 64 + k] = h; g_w2l[1][n * 64 + k] = l;
    } else if (tid < 57344) {          // Wd1 [128][64] -> [64][128]
        int i = tid - 49152; int k = i >> 6, n = i & 63;
        __bf16 h, l; split1(Wd1[i], h, l);
        g_wd1h[n * 128 + k] = h; g_wd1l[n * 128 + k] = l;
    }
}

// ---------------------------------------------------------------------------
// Counting sort of edges by receiver.
// ---------------------------------------------------------------------------
__global__ void hist_kernel(const int* __restrict__ rcv, uint32_t* __restrict__ hist) {
    int e = blockIdx.x * blockDim.x + threadIdx.x;
    if (e < NE) atomicAdd(hist + rcv[e], 1u);
}

__global__ void scan1_kernel(const uint32_t* __restrict__ hist,
                             uint32_t* __restrict__ pre, uint32_t* __restrict__ bsum) {
    __shared__ uint32_t s[256];
    int t = threadIdx.x;
    int i = blockIdx.x * 256 + t;
    uint32_t v = (i < NN) ? hist[i] : 0u;
    s[t] = v; __syncthreads();
    #pragma unroll
    for (int off = 1; off < 256; off <<= 1) {
        uint32_t tv = (t >= off) ? s[t - off] : 0u;
        __syncthreads();
        s[t] += tv; __syncthreads();
    }
    if (i < NN) pre[i] = s[t] - v;
    if (t == 255) bsum[blockIdx.x] = s[255];
}

__global__ void scan2_kernel(uint32_t* __restrict__ bsum, int nb) {
    __shared__ uint32_t s[256];
    int t = threadIdx.x;
    uint32_t v = (t < nb) ? bsum[t] : 0u;
    s[t] = v; __syncthreads();
    #pragma unroll
    for (int off = 1; off < 256; off <<= 1) {
        uint32_t tv = (t >= off) ? s[t - off] : 0u;
        __syncthreads();
        s[t] += tv; __syncthreads();
    }
    if (t < nb) bsum[t] = s[t] - v;
}

__global__ void scan3_kernel(const uint32_t* __restrict__ pre,
                             const uint32_t* __restrict__ bsum,
                             uint32_t* __restrict__ row_off) {
    int i = blockIdx.x * 256 + threadIdx.x;
    if (i < NN) row_off[i] = pre[i] + bsum[blockIdx.x];
    if (i == 0) row_off[NN] = NE;
}

__global__ void rank_scatter_kernel(const int* __restrict__ rcv,
                                    const uint32_t* __restrict__ row_off,
                                    uint32_t* __restrict__ cursor,
                                    uint32_t* __restrict__ perm) {
    int e = blockIdx.x * blockDim.x + threadIdx.x;
    if (e < NE) {
        int r = rcv[e];
        uint32_t k = atomicAdd(cursor + r, 1u);
        perm[row_off[r] + k] = e;
    }
}

// ---------------------------------------------------------------------------
// node_w1_kernel: per-node half-products of GEMM1.
//   hrp[n] = src[n] @ W1_top + b1   (receiver term, bias folded)
//   hsp[n] = src[n] @ W1_bot        (sender term)
// mean-mode (row_off != null): src is seg; scale rows by 1/cnt and rezero seg.
// 64 nodes/block, 4 waves; wave w owns out-cols 16w..16w+16 of both outputs.
// ---------------------------------------------------------------------------
__global__ __launch_bounds__(256) void node_w1_kernel(
    const float* __restrict__ src, const uint32_t* __restrict__ row_off,
    float* __restrict__ seg_rz, const float* __restrict__ b1,
    float* __restrict__ hrp, float* __restrict__ hsp, int layer)
{
    __shared__ __align__(16) uint32_t sA[64 * 132];   // packed split rows, stride 132
    const int t = threadIdx.x;
    const int w = t >> 6, lane = t & 63, quad = lane >> 4, l16 = lane & 15;
    const int node0 = blockIdx.x * 64;

    // ---- staging: thread t -> row r=t>>2, k-chunk (t&3)*32, split+pack -----
    {
        const int r = t >> 2, kq = (t & 3) * 32;
        const int node = node0 + r;
        f32x4 v[8];
        if (node < NN) {
            const float* p = src + (size_t)node * 128 + kq;
            #pragma unroll
            for (int i = 0; i < 8; ++i) v[i] = *(const f32x4*)(p + 4 * i);
            if (row_off) {
                uint32_t c = row_off[node + 1] - row_off[node];
                float inv = (c > 0u) ? 1.0f / (float)c : 0.f;
                #pragma unroll
                for (int i = 0; i < 8; ++i) v[i] = v[i] * inv;
                float* z = seg_rz + (size_t)node * 128 + kq;
                #pragma unroll
                for (int i = 0; i < 8; ++i) *(f32x4*)(z + 4 * i) = (f32x4){0.f, 0.f, 0.f, 0.f};
            }
        } else {
            #pragma unroll
            for (int i = 0; i < 8; ++i) v[i] = (f32x4){0.f, 0.f, 0.f, 0.f};
        }
        uint32_t* d = sA + r * 132 + kq;
        const int rot = t & 3;                      // stagger i to spread banks
        #pragma unroll
        for (int i = 0; i < 8; ++i) {
            const int ii = (i + rot) & 7;
            f32x4 vv = v[ii];
            uint4 pk;
            pk.x = pack_split(vv[0]); pk.y = pack_split(vv[1]);
            pk.z = pack_split(vv[2]); pk.w = pack_split(vv[3]);
            *(uint4*)(d + 4 * ii) = pk;
        }
    }
    __syncthreads();

    // ---- GEMM: [64 x 128] @ ([128 x 16] top, [128 x 16] bot) per wave ------
    const int n = 16 * w + l16;
    const __bf16* w1hp = g_w1h[layer] + n * 256;
    const __bf16* w1lp = g_w1l[layer] + n * 256;
    f32x4 acc[4][2] = {};
    #pragma unroll
    for (int kq = 0; kq < 4; ++kq) {
        const int k0 = kq * 32 + quad * 8;
        bf16x8 bh0 = *(const bf16x8*)(w1hp + k0);
        bf16x8 bl0 = *(const bf16x8*)(w1lp + k0);
        bf16x8 bh1 = *(const bf16x8*)(w1hp + 128 + k0);
        bf16x8 bl1 = *(const bf16x8*)(w1lp + 128 + k0);
        #pragma unroll
        for (int st = 0; st < 4; ++st) {
            const uint32_t* ap = sA + (16 * st + l16) * 132 + k0;
            uint4 u0 = *(const uint4*)ap, u1 = *(const uint4*)(ap + 4);
            bf16x8 ah, al; unpack8(u0, u1, ah, al);
            acc[st][0] = __builtin_amdgcn_mfma_f32_16x16x32_bf16(ah, bh0, acc[st][0], 0, 0, 0);
            acc[st][0] = __builtin_amdgcn_mfma_f32_16x16x32_bf16(al, bh0, acc[st][0], 0, 0, 0);
            acc[st][0] = __builtin_amdgcn_mfma_f32_16x16x32_bf16(ah, bl0, acc[st][0], 0, 0, 0);
            acc[st][1] = __builtin_amdgcn_mfma_f32_16x16x32_bf16(ah, bh1, acc[st][1], 0, 0, 0);
            acc[st][1] = __builtin_amdgcn_mfma_f32_16x16x32_bf16(al, bh1, acc[st][1], 0, 0, 0);
            acc[st][1] = __builtin_amdgcn_mfma_f32_16x16x32_bf16(ah, bl1, acc[st][1], 0, 0, 0);
        }
    }

    const float b1v = b1[n];
    #pragma unroll
    for (int st = 0; st < 4; ++st) {
        #pragma unroll
        for (int r = 0; r < 4; ++r) {
            const int node = node0 + 16 * st + quad * 4 + r;
            if (node < NN) {
                hrp[(size_t)node * 64 + n] = acc[st][0][r] + b1v;
                hsp[(size_t)node * 64 + n] = acc[st][1][r];
            }
        }
    }
}

// ---------------------------------------------------------------------------
// edge_gemm2_kernel: 64 sorted edges/block.
//   h[e] = relu(hrp[recv[e]] + hsp[send[e]])   (bias already in hrp)
//   msg  = relu(h @ W2 + b2) ; run-reduced atomicAdd into seg[recv].
// Wave w owns out-cols 32w..32w+32 (two 16-col tiles).
// ---------------------------------------------------------------------------
__global__ __launch_bounds__(256) void edge_gemm2_kernel(
    const float* __restrict__ hrp, const float* __restrict__ hsp,
    const int* __restrict__ receivers, const int* __restrict__ senders,
    const uint32_t* __restrict__ perm,
    const float* __restrict__ b2,
    float* __restrict__ seg, int layer)
{
    __shared__ __align__(16) uint32_t sH[64 * 68];    // packed h, stride 68
    __shared__ int sRecv[64];

    const int t = threadIdx.x;
    const int w = t >> 6, lane = t & 63, quad = lane >> 4, l16 = lane & 15;
    const int e0 = blockIdx.x * 64;

    // ---- staging: thread t -> edge e=t>>2, k-chunk (t&3)*16 ----------------
    {
        const int e = t >> 2, kq = (t & 3) * 16;
        const int ei = (int)perm[e0 + e];
        const int rv = receivers[ei], sv = senders[ei];
        if ((t & 3) == 0) sRecv[e] = rv;
        const float* hp = hrp + (size_t)rv * 64 + kq;
        const float* sp = hsp + (size_t)sv * 64 + kq;
        f32x4 a[4], b[4];
        #pragma unroll
        for (int i = 0; i < 4; ++i) { a[i] = *(const f32x4*)(hp + 4 * i);
                                      b[i] = *(const f32x4*)(sp + 4 * i); }
        uint32_t* d = sH + e * 68 + kq;
        #pragma unroll
        for (int i = 0; i < 4; ++i) {
            uint4 pk;
            pk.x = pack_split(fmaxf(a[i][0] + b[i][0], 0.f));
            pk.y = pack_split(fmaxf(a[i][1] + b[i][1], 0.f));
            pk.z = pack_split(fmaxf(a[i][2] + b[i][2], 0.f));
            pk.w = pack_split(fmaxf(a[i][3] + b[i][3], 0.f));
            *(uint4*)(d + 4 * i) = pk;
        }
    }
    __syncthreads();

    // ---- GEMM2: [64 x 64] @ [64 x 32-cols-per-wave] ------------------------
    const int ncol0 = 32 * w + l16;
    const __bf16* w2hp = g_w2h[layer];
    const __bf16* w2lp = g_w2l[layer];
    f32x4 acc[4][2] = {};
    #pragma unroll
    for (int s = 0; s < 2; ++s) {
        const int k0 = s * 32 + quad * 8;
        bf16x8 bh[2], bl[2];
        #pragma unroll
        for (int c2 = 0; c2 < 2; ++c2) {
            const int n = ncol0 + 16 * c2;
            bh[c2] = *(const bf16x8*)(w2hp + n * 64 + k0);
            bl[c2] = *(const bf16x8*)(w2lp + n * 64 + k0);
        }
        #pragma unroll
        for (int st = 0; st < 4; ++st) {
            const uint32_t* ap = sH + (16 * st + l16) * 68 + k0;
            uint4 u0 = *(const uint4*)ap, u1 = *(const uint4*)(ap + 4);
            bf16x8 ah, al; unpack8(u0, u1, ah, al);
            #pragma unroll
            for (int c2 = 0; c2 < 2; ++c2) {
                acc[st][c2] = __builtin_amdgcn_mfma_f32_16x16x32_bf16(ah, bh[c2], acc[st][c2], 0, 0, 0);
                acc[st][c2] = __builtin_amdgcn_mfma_f32_16x16x32_bf16(al, bh[c2], acc[st][c2], 0, 0, 0);
                acc[st][c2] = __builtin_amdgcn_mfma_f32_16x16x32_bf16(ah, bl[c2], acc[st][c2], 0, 0, 0);
            }
        }
    }

    // ---- epilogue: relu(+b2); run-reduce equal receivers; atomic -----------
    #pragma unroll
    for (int c2 = 0; c2 < 2; ++c2) {
        const int n = ncol0 + 16 * c2;
        const float bv = b2[n];
        #pragma unroll
        for (int st = 0; st < 4; ++st) {
            const int ebase = 16 * st + quad * 4;
            int rc[4]; float v[4];
            #pragma unroll
            for (int r = 0; r < 4; ++r) {
                rc[r] = sRecv[ebase + r];
                v[r]  = fmaxf(acc[st][c2][r] + bv, 0.f);
            }
            int prev = rc[0];
            float sm = v[0];
            #pragma unroll
            for (int r = 1; r < 4; ++r) {
                if (rc[r] == prev) {
                    sm += v[r];
                } else {
                    atomicAdd(seg + (size_t)prev * 128 + n, sm);
                    prev = rc[r];
                    sm = v[r];
                }
            }
            atomicAdd(seg + (size_t)prev * 128 + n, sm);
        }
    }
}

// ---------------------------------------------------------------------------
// tail_kernel: per node: m = seg/cnt ; tcol = relu(m @ Wd1 + bd1) ;
// out = tcol @ Wd2 + bd2. 64 nodes/block, MFMA + shuffle reduce.
// ---------------------------------------------------------------------------
__global__ __launch_bounds__(256) void tail_kernel(
    const float* __restrict__ seg, const uint32_t* __restrict__ row_off,
    const float* __restrict__ bd1, const float* __restrict__ Wd2,
    const float* __restrict__ bd2, float* __restrict__ out)
{
    __shared__ __align__(16) uint32_t sA[64 * 132];
    __shared__ float sOut[64];
    const int t = threadIdx.x;
    const int w = t >> 6, lane = t & 63, quad = lane >> 4, l16 = lane & 15;
    const int node0 = blockIdx.x * 64;

    if (t < 64) sOut[t] = 0.f;

    {
        const int r = t >> 2, kq = (t & 3) * 32;
        const int node = node0 + r;
        f32x4 v[8];
        if (node < NN) {
            uint32_t c = row_off[node + 1] - row_off[node];
            float inv = (c > 0u) ? 1.0f / (float)c : 0.f;
            const float* p = seg + (size_t)node * 128 + kq;
            #pragma unroll
            for (int i = 0; i < 8; ++i) v[i] = *(const f32x4*)(p + 4 * i) * inv;
        } else {
            #pragma unroll
            for (int i = 0; i < 8; ++i) v[i] = (f32x4){0.f, 0.f, 0.f, 0.f};
        }
        uint32_t* d = sA + r * 132 + kq;
        const int rot = t & 3;
        #pragma unroll
        for (int i = 0; i < 8; ++i) {
            const int ii = (i + rot) & 7;
            f32x4 vv = v[ii];
            uint4 pk;
            pk.x = pack_split(vv[0]); pk.y = pack_split(vv[1]);
            pk.z = pack_split(vv[2]); pk.w = pack_split(vv[3]);
            *(uint4*)(d + 4 * ii) = pk;
        }
    }
    __syncthreads();

    const int n = 16 * w + l16;
    const __bf16* bhp = g_wd1h + n * 128;
    const __bf16* blp = g_wd1l + n * 128;
    f32x4 acc[4] = {};
    #pragma unroll
    for (int kq = 0; kq < 4; ++kq) {
        const int k0 = kq * 32 + quad * 8;
        bf16x8 bh = *(const bf16x8*)(bhp + k0);
        bf16x8 bl = *(const bf16x8*)(blp + k0);
        #pragma unroll
        for (int st = 0; st < 4; ++st) {
            const uint32_t* ap = sA + (16 * st + l16) * 132 + k0;
            uint4 u0 = *(const uint4*)ap, u1 = *(const uint4*)(ap + 4);
            bf16x8 ah, al; unpack8(u0, u1, ah, al);
            acc[st] = __builtin_amdgcn_mfma_f32_16x16x32_bf16(ah, bh, acc[st], 0, 0, 0);
            acc[st] = __builtin_amdgcn_mfma_f32_16x16x32_bf16(al, bh, acc[st], 0, 0, 0);
            acc[st] = __builtin_amdgcn_mfma_f32_16x16x32_bf16(ah, bl, acc[st], 0, 0, 0);
        }
    }

    const float bd1v = bd1[n];
    const float wd2v = Wd2[n];
    #pragma unroll
    for (int st = 0; st < 4; ++st) {
        #pragma unroll
        for (int r = 0; r < 4; ++r) {
            float p = fmaxf(acc[st][r] + bd1v, 0.f) * wd2v;
            p += __shfl_xor(p, 1, 16);
            p += __shfl_xor(p, 2, 16);
            p += __shfl_xor(p, 4, 16);
            p += __shfl_xor(p, 8, 16);
            if (l16 == 0) atomicAdd(&sOut[16 * st + quad * 4 + r], p);
        }
    }
    __syncthreads();
    if (t < 64) {
        const int node = node0 + t;
        if (node < NN) out[node] = sOut[t] + bd2[0];
    }
}

// ---------------------------------------------------------------------------
extern "C" void kernel_launch(void* const* d_in, const int* in_sizes, int n_in,
                              void* d_out, int out_size, void* d_ws, size_t ws_size,
                              hipStream_t stream) {
    const float* x   = (const float*)d_in[0];
    const int*   snd = (const int*)  d_in[1];
    const int*   rcv = (const int*)  d_in[2];
    const float* W1a = (const float*)d_in[3];
    const float* b1a = (const float*)d_in[4];
    const float* W2a = (const float*)d_in[5];
    const float* b2a = (const float*)d_in[6];
    const float* W1b = (const float*)d_in[7];
    const float* b1b = (const float*)d_in[8];
    const float* W2b = (const float*)d_in[9];
    const float* b2b = (const float*)d_in[10];
    const float* Wd1 = (const float*)d_in[11];
    const float* bd1 = (const float*)d_in[12];
    const float* Wd2 = (const float*)d_in[13];
    const float* bd2 = (const float*)d_in[14];
    float* out = (float*)d_out;

    // ws layout: seg [NN*128 f32] | hist [NN] | cursor [NN] | row_off [NN+1] |
    //            pre [NN] | bsum [256] | perm [NE] | hrp [NN*64] | hsp [NN*64]
    float*    seg     = (float*)d_ws;
    uint32_t* hist    = (uint32_t*)(seg + (size_t)NN * 128);
    uint32_t* cursor  = hist + NN;
    uint32_t* row_off = cursor + NN;
    uint32_t* pre     = row_off + (NN + 1);
    uint32_t* bsum    = pre + NN;
    uint32_t* perm    = bsum + 256;
    float*    hrp     = (float*)(perm + NE);
    float*    hsp     = hrp + (size_t)NN * 64;

    hipMemsetAsync(seg, 0, ((size_t)NN * 128 + 2 * NN) * sizeof(float), stream);

    const int nb  = (NN + 255) / 256;   // 196
    const int nbn = (NN + 63) / 64;     // 782

    hipLaunchKernelGGL(split_w_kernel, dim3(224), dim3(256), 0, stream,
                       W1a, W2a, W1b, W2b, Wd1);
    hipLaunchKernelGGL(hist_kernel, dim3((NE + 255) / 256), dim3(256), 0, stream, rcv, hist);
    hipLaunchKernelGGL(scan1_kernel, dim3(nb), dim3(256), 0, stream, hist, pre, bsum);
    hipLaunchKernelGGL(scan2_kernel, dim3(1), dim3(256), 0, stream, bsum, nb);
    hipLaunchKernelGGL(scan3_kernel, dim3(nb), dim3(256), 0, stream, pre, bsum, row_off);
    hipLaunchKernelGGL(rank_scatter_kernel, dim3((NE + 255) / 256), dim3(256), 0, stream,
                       rcv, row_off, cursor, perm);

    // layer 1
    hipLaunchKernelGGL(node_w1_kernel, dim3(nbn), dim3(256), 0, stream,
                       x, (const uint32_t*)nullptr, (float*)nullptr, b1a, hrp, hsp, 0);
    hipLaunchKernelGGL(edge_gemm2_kernel, dim3(NE / 64), dim3(256), 0, stream,
                       hrp, hsp, rcv, snd, perm, b2a, seg, 0);
    // layer 2 (node_w1 mean-mode reads seg, scales 1/cnt, rezeros seg)
    hipLaunchKernelGGL(node_w1_kernel, dim3(nbn), dim3(256), 0, stream,
                       seg, row_off, seg, b1b, hrp, hsp, 1);
    hipLaunchKernelGGL(edge_gemm2_kernel, dim3(NE / 64), dim3(256), 0, stream,
                       hrp, hsp, rcv, snd, perm, b2b, seg, 1);
    // dense tail (computes mean inline)
    hipLaunchKernelGGL(tail_kernel, dim3(nbn), dim3(256), 0, stream,
                       seg, row_off, bd1, Wd2, bd2, out);
}

// Round 6
// 736.166 us; speedup vs baseline: 3.9930x; 1.0987x over previous
//
#include <hip/hip_runtime.h>
#include <hip/hip_bf16.h>
#include <cstdint>
#include <cstddef>

#define NN 50000
#define NE 800000

typedef __bf16 bf16x8 __attribute__((ext_vector_type(8)));
typedef float  f32x4  __attribute__((ext_vector_type(4)));

// Pre-split, pre-transposed weights (hi/lo bf16 decomposition of fp32).
// W1t: [n][k] n<64,k<256 ; W2t: [n][k] n<128,k<64 ; Wd1t: [n][k] n<64,k<128.
__device__ __bf16 g_w1h[2][64 * 256];
__device__ __bf16 g_w1l[2][64 * 256];
__device__ __bf16 g_w2h[2][128 * 64];
__device__ __bf16 g_w2l[2][128 * 64];
__device__ __bf16 g_wd1h[64 * 128];
__device__ __bf16 g_wd1l[64 * 128];

__device__ __forceinline__ void split1(float v, __bf16& h, __bf16& l) {
    h = (__bf16)v;
    l = (__bf16)(v - (float)h);
}

// pack: low16 = hi bf16 bits, high16 = lo bf16 bits
__device__ __forceinline__ uint32_t pack_split(float v) {
    __bf16 h, l; split1(v, h, l);
    return (uint32_t)__builtin_bit_cast(unsigned short, h)
         | ((uint32_t)__builtin_bit_cast(unsigned short, l) << 16);
}

// 8 packed u32 (k0..k0+7) -> hi-plane and lo-plane bf16x8 fragments
__device__ __forceinline__ void unpack8(uint4 u0, uint4 u1, bf16x8& ah, bf16x8& al) {
    const uint32_t a[8] = {u0.x, u0.y, u0.z, u0.w, u1.x, u1.y, u1.z, u1.w};
    union { uint32_t u[4]; bf16x8 v; } H, L;
    #pragma unroll
    for (int i = 0; i < 4; ++i) {
        H.u[i] = (a[2*i] & 0xffffu) | (a[2*i+1] << 16);
        L.u[i] = (a[2*i] >> 16)     | (a[2*i+1] & 0xffff0000u);
    }
    ah = H.v; al = L.v;
}

// ---------------------------------------------------------------------------
// pre_kernel: blocks [0,224) split weights; blocks [224,224+3125) histogram
// ---------------------------------------------------------------------------
__global__ __launch_bounds__(256) void pre_kernel(
    const float* __restrict__ W1a, const float* __restrict__ W2a,
    const float* __restrict__ W1b, const float* __restrict__ W2b,
    const float* __restrict__ Wd1,
    const int* __restrict__ rcv, uint32_t* __restrict__ hist)
{
    const int b = blockIdx.x, t = threadIdx.x;
    if (b < 224) {
        int tid = b * 256 + t;
        if (tid < 16384) {                 // W1a [256][64] -> [64][256]
            int k = tid >> 6, n = tid & 63;
            __bf16 h, l; split1(W1a[tid], h, l);
            g_w1h[0][n * 256 + k] = h; g_w1l[0][n * 256 + k] = l;
        } else if (tid < 24576) {          // W2a [64][128] -> [128][64]
            int i = tid - 16384; int k = i >> 7, n = i & 127;
            __bf16 h, l; split1(W2a[i], h, l);
            g_w2h[0][n * 64 + k] = h; g_w2l[0][n * 64 + k] = l;
        } else if (tid < 40960) {          // W1b
            int i = tid - 24576; int k = i >> 6, n = i & 63;
            __bf16 h, l; split1(W1b[i], h, l);
            g_w1h[1][n * 256 + k] = h; g_w1l[1][n * 256 + k] = l;
        } else if (tid < 49152) {          // W2b
            int i = tid - 40960; int k = i >> 7, n = i & 127;
            __bf16 h, l; split1(W2b[i], h, l);
            g_w2h[1][n * 64 + k] = h; g_w2l[1][n * 64 + k] = l;
        } else if (tid < 57344) {          // Wd1 [128][64] -> [64][128]
            int i = tid - 49152; int k = i >> 6, n = i & 63;
            __bf16 h, l; split1(Wd1[i], h, l);
            g_wd1h[n * 128 + k] = h; g_wd1l[n * 128 + k] = l;
        }
    } else {
        int e = (b - 224) * 256 + t;
        if (e < NE) atomicAdd(hist + rcv[e], 1u);
    }
}

// ---------------------------------------------------------------------------
// scan chain for counting sort
// ---------------------------------------------------------------------------
__global__ void scan1_kernel(const uint32_t* __restrict__ hist,
                             uint32_t* __restrict__ pre, uint32_t* __restrict__ bsum) {
    __shared__ uint32_t s[256];
    int t = threadIdx.x;
    int i = blockIdx.x * 256 + t;
    uint32_t v = (i < NN) ? hist[i] : 0u;
    s[t] = v; __syncthreads();
    #pragma unroll
    for (int off = 1; off < 256; off <<= 1) {
        uint32_t tv = (t >= off) ? s[t - off] : 0u;
        __syncthreads();
        s[t] += tv; __syncthreads();
    }
    if (i < NN) pre[i] = s[t] - v;
    if (t == 255) bsum[blockIdx.x] = s[255];
}

__global__ void scan2_kernel(uint32_t* __restrict__ bsum, int nb) {
    __shared__ uint32_t s[256];
    int t = threadIdx.x;
    uint32_t v = (t < nb) ? bsum[t] : 0u;
    s[t] = v; __syncthreads();
    #pragma unroll
    for (int off = 1; off < 256; off <<= 1) {
        uint32_t tv = (t >= off) ? s[t - off] : 0u;
        __syncthreads();
        s[t] += tv; __syncthreads();
    }
    if (t < nb) bsum[t] = s[t] - v;
}

__global__ void scan3_kernel(const uint32_t* __restrict__ pre,
                             const uint32_t* __restrict__ bsum,
                             uint32_t* __restrict__ row_off) {
    int i = blockIdx.x * 256 + threadIdx.x;
    if (i < NN) row_off[i] = pre[i] + bsum[blockIdx.x];
    if (i == 0) row_off[NN] = NE;
}

// ---------------------------------------------------------------------------
// node_w1_body: per-node half-products of GEMM1 (shared by two kernels).
//   hrp[n] = src[n] @ W1_top + b1 ; hsp[n] = src[n] @ W1_bot
// mean-mode (row_off != null): scale by 1/cnt and rezero seg.
// ---------------------------------------------------------------------------
__device__ __forceinline__ void node_w1_body(
    const float* __restrict__ src, const uint32_t* __restrict__ row_off,
    float* __restrict__ seg_rz, const float* __restrict__ b1,
    float* __restrict__ hrp, float* __restrict__ hsp, int layer, int blk)
{
    __shared__ __align__(16) uint32_t sA[64 * 132];
    const int t = threadIdx.x;
    const int w = t >> 6, lane = t & 63, quad = lane >> 4, l16 = lane & 15;
    const int node0 = blk * 64;

    {
        const int r = t >> 2, kq = (t & 3) * 32;
        const int node = node0 + r;
        f32x4 v[8];
        if (node < NN) {
            const float* p = src + (size_t)node * 128 + kq;
            #pragma unroll
            for (int i = 0; i < 8; ++i) v[i] = *(const f32x4*)(p + 4 * i);
            if (row_off) {
                uint32_t c = row_off[node + 1] - row_off[node];
                float inv = (c > 0u) ? 1.0f / (float)c : 0.f;
                #pragma unroll
                for (int i = 0; i < 8; ++i) v[i] = v[i] * inv;
                float* z = seg_rz + (size_t)node * 128 + kq;
                #pragma unroll
                for (int i = 0; i < 8; ++i) *(f32x4*)(z + 4 * i) = (f32x4){0.f, 0.f, 0.f, 0.f};
            }
        } else {
            #pragma unroll
            for (int i = 0; i < 8; ++i) v[i] = (f32x4){0.f, 0.f, 0.f, 0.f};
        }
        uint32_t* d = sA + r * 132 + kq;
        const int rot = t & 3;
        #pragma unroll
        for (int i = 0; i < 8; ++i) {
            const int ii = (i + rot) & 7;
            f32x4 vv = v[ii];
            uint4 pk;
            pk.x = pack_split(vv[0]); pk.y = pack_split(vv[1]);
            pk.z = pack_split(vv[2]); pk.w = pack_split(vv[3]);
            *(uint4*)(d + 4 * ii) = pk;
        }
    }
    __syncthreads();

    const int n = 16 * w + l16;
    const __bf16* w1hp = g_w1h[layer] + n * 256;
    const __bf16* w1lp = g_w1l[layer] + n * 256;
    f32x4 acc[4][2] = {};
    #pragma unroll
    for (int kq = 0; kq < 4; ++kq) {
        const int k0 = kq * 32 + quad * 8;
        bf16x8 bh0 = *(const bf16x8*)(w1hp + k0);
        bf16x8 bl0 = *(const bf16x8*)(w1lp + k0);
        bf16x8 bh1 = *(const bf16x8*)(w1hp + 128 + k0);
        bf16x8 bl1 = *(const bf16x8*)(w1lp + 128 + k0);
        #pragma unroll
        for (int st = 0; st < 4; ++st) {
            const uint32_t* ap = sA + (16 * st + l16) * 132 + k0;
            uint4 u0 = *(const uint4*)ap, u1 = *(const uint4*)(ap + 4);
            bf16x8 ah, al; unpack8(u0, u1, ah, al);
            acc[st][0] = __builtin_amdgcn_mfma_f32_16x16x32_bf16(ah, bh0, acc[st][0], 0, 0, 0);
            acc[st][0] = __builtin_amdgcn_mfma_f32_16x16x32_bf16(al, bh0, acc[st][0], 0, 0, 0);
            acc[st][0] = __builtin_amdgcn_mfma_f32_16x16x32_bf16(ah, bl0, acc[st][0], 0, 0, 0);
            acc[st][1] = __builtin_amdgcn_mfma_f32_16x16x32_bf16(ah, bh1, acc[st][1], 0, 0, 0);
            acc[st][1] = __builtin_amdgcn_mfma_f32_16x16x32_bf16(al, bh1, acc[st][1], 0, 0, 0);
            acc[st][1] = __builtin_amdgcn_mfma_f32_16x16x32_bf16(ah, bl1, acc[st][1], 0, 0, 0);
        }
    }

    const float b1v = b1[n];
    #pragma unroll
    for (int st = 0; st < 4; ++st) {
        #pragma unroll
        for (int r = 0; r < 4; ++r) {
            const int node = node0 + 16 * st + quad * 4 + r;
            if (node < NN) {
                hrp[(size_t)node * 64 + n] = acc[st][0][r] + b1v;
                hsp[(size_t)node * 64 + n] = acc[st][1][r];
            }
        }
    }
}

// standalone node_w1 (layer-2 mean mode)
__global__ __launch_bounds__(256) void node_w1_kernel(
    const float* __restrict__ src, const uint32_t* __restrict__ row_off,
    float* __restrict__ seg_rz, const float* __restrict__ b1,
    float* __restrict__ hrp, float* __restrict__ hsp, int layer)
{
    node_w1_body(src, row_off, seg_rz, b1, hrp, hsp, layer, blockIdx.x);
}

// ---------------------------------------------------------------------------
// mid_kernel: blocks [0,nbn) = node_w1 layer-0; rest = rank-scatter building
// sorted (recv,send) pairs.
// ---------------------------------------------------------------------------
__global__ __launch_bounds__(256) void mid_kernel(
    const float* __restrict__ x, const float* __restrict__ b1a,
    float* __restrict__ hrp, float* __restrict__ hsp,
    const int* __restrict__ rcv, const int* __restrict__ snd,
    const uint32_t* __restrict__ row_off, uint32_t* __restrict__ cursor,
    int2* __restrict__ srt, int nbn)
{
    if ((int)blockIdx.x < nbn) {
        node_w1_body(x, (const uint32_t*)nullptr, (float*)nullptr, b1a, hrp, hsp, 0,
                     blockIdx.x);
    } else {
        int e = (blockIdx.x - nbn) * 256 + threadIdx.x;
        if (e < NE) {
            int r = rcv[e];
            uint32_t k = atomicAdd(cursor + r, 1u);
            srt[row_off[r] + k] = make_int2(r, snd[e]);
        }
    }
}

// ---------------------------------------------------------------------------
// gemm2_compute: one 64-edge tile's GEMM2 + epilogue (strip-uniform fast path)
// ---------------------------------------------------------------------------
__device__ __forceinline__ void gemm2_compute(
    const uint32_t* __restrict__ sHb, const int* __restrict__ sRecvB,
    const __bf16* __restrict__ w2hp, const __bf16* __restrict__ w2lp,
    const float* __restrict__ b2, float* __restrict__ seg,
    int w, int quad, int l16)
{
    const int ncol0 = 32 * w + l16;
    f32x4 acc[4][2] = {};
    #pragma unroll
    for (int s = 0; s < 2; ++s) {
        const int k0 = s * 32 + quad * 8;
        bf16x8 bh[2], bl[2];
        #pragma unroll
        for (int c2 = 0; c2 < 2; ++c2) {
            const int n = ncol0 + 16 * c2;
            bh[c2] = *(const bf16x8*)(w2hp + n * 64 + k0);
            bl[c2] = *(const bf16x8*)(w2lp + n * 64 + k0);
        }
        #pragma unroll
        for (int st = 0; st < 4; ++st) {
            const uint32_t* ap = sHb + (16 * st + l16) * 68 + k0;
            uint4 u0 = *(const uint4*)ap, u1 = *(const uint4*)(ap + 4);
            bf16x8 ah, al; unpack8(u0, u1, ah, al);
            #pragma unroll
            for (int c2 = 0; c2 < 2; ++c2) {
                acc[st][c2] = __builtin_amdgcn_mfma_f32_16x16x32_bf16(ah, bh[c2], acc[st][c2], 0, 0, 0);
                acc[st][c2] = __builtin_amdgcn_mfma_f32_16x16x32_bf16(al, bh[c2], acc[st][c2], 0, 0, 0);
                acc[st][c2] = __builtin_amdgcn_mfma_f32_16x16x32_bf16(ah, bl[c2], acc[st][c2], 0, 0, 0);
            }
        }
    }

    #pragma unroll
    for (int c2 = 0; c2 < 2; ++c2) {
        const int n = ncol0 + 16 * c2;
        const float bv = b2[n];
        #pragma unroll
        for (int st = 0; st < 4; ++st) {
            const int base = 16 * st;
            float v[4];
            #pragma unroll
            for (int r = 0; r < 4; ++r)
                v[r] = fmaxf(acc[st][c2][r] + bv, 0.f);
            const int rcHead = sRecvB[base];
            const int rcTail = sRecvB[base + 15];
            if (rcHead == rcTail) {
                // whole 16-edge strip -> one receiver: cross-quad reduce
                float sm = (v[0] + v[1]) + (v[2] + v[3]);
                sm += __shfl_xor(sm, 16);
                sm += __shfl_xor(sm, 32);
                if (quad == 0) atomicAdd(seg + (size_t)rcHead * 128 + n, sm);
            } else {
                int rc[4];
                #pragma unroll
                for (int r = 0; r < 4; ++r) rc[r] = sRecvB[base + quad * 4 + r];
                int prev = rc[0];
                float sm = v[0];
                #pragma unroll
                for (int r = 1; r < 4; ++r) {
                    if (rc[r] == prev) {
                        sm += v[r];
                    } else {
                        atomicAdd(seg + (size_t)prev * 128 + n, sm);
                        prev = rc[r];
                        sm = v[r];
                    }
                }
                atomicAdd(seg + (size_t)prev * 128 + n, sm);
            }
        }
    }
}

// ---------------------------------------------------------------------------
// edge_gemm2_kernel: 128 sorted edges/block as two pipelined 64-edge tiles.
//   h[e] = relu(hrp[recv] + hsp[send]) ; msg = relu(h @ W2 + b2) ;
//   run/strip-reduced atomicAdd into seg[recv].
// ---------------------------------------------------------------------------
__global__ __launch_bounds__(256) void edge_gemm2_kernel(
    const float* __restrict__ hrp, const float* __restrict__ hsp,
    const int2* __restrict__ srt,
    const float* __restrict__ b2,
    float* __restrict__ seg, int layer)
{
    __shared__ __align__(16) uint32_t sH[2][64 * 68];
    __shared__ int sRecv[2][64];

    const int t = threadIdx.x;
    const int w = t >> 6, lane = t & 63, quad = lane >> 4, l16 = lane & 15;
    const int e0 = blockIdx.x * 128;
    const int eL = t >> 2;              // local edge 0..63
    const int kq = (t & 3) * 16;        // f32 k-offset

    const __bf16* w2hp = g_w2h[layer];
    const __bf16* w2lp = g_w2l[layer];

    // ---- stage tile 0 ------------------------------------------------------
    int2 rs0 = srt[e0 + eL];
    f32x4 a0[4], b0[4];
    {
        const float* hp = hrp + (size_t)rs0.x * 64 + kq;
        const float* sp = hsp + (size_t)rs0.y * 64 + kq;
        #pragma unroll
        for (int i = 0; i < 4; ++i) { a0[i] = *(const f32x4*)(hp + 4 * i);
                                      b0[i] = *(const f32x4*)(sp + 4 * i); }
    }
    if ((t & 3) == 0) sRecv[0][eL] = rs0.x;
    {
        uint32_t* d = sH[0] + eL * 68 + kq;
        #pragma unroll
        for (int i = 0; i < 4; ++i) {
            uint4 pk;
            pk.x = pack_split(fmaxf(a0[i][0] + b0[i][0], 0.f));
            pk.y = pack_split(fmaxf(a0[i][1] + b0[i][1], 0.f));
            pk.z = pack_split(fmaxf(a0[i][2] + b0[i][2], 0.f));
            pk.w = pack_split(fmaxf(a0[i][3] + b0[i][3], 0.f));
            *(uint4*)(d + 4 * i) = pk;
        }
    }
    __syncthreads();

    // ---- prefetch tile 1 (loads in flight during tile-0 compute) -----------
    int2 rs1 = srt[e0 + 64 + eL];
    f32x4 a1[4], b1v[4];
    {
        const float* hp = hrp + (size_t)rs1.x * 64 + kq;
        const float* sp = hsp + (size_t)rs1.y * 64 + kq;
        #pragma unroll
        for (int i = 0; i < 4; ++i) { a1[i] = *(const f32x4*)(hp + 4 * i);
                                      b1v[i] = *(const f32x4*)(sp + 4 * i); }
    }

    // ---- compute tile 0 ----------------------------------------------------
    gemm2_compute(sH[0], sRecv[0], w2hp, w2lp, b2, seg, w, quad, l16);

    // ---- pack + store tile 1 ----------------------------------------------
    if ((t & 3) == 0) sRecv[1][eL] = rs1.x;
    {
        uint32_t* d = sH[1] + eL * 68 + kq;
        #pragma unroll
        for (int i = 0; i < 4; ++i) {
            uint4 pk;
            pk.x = pack_split(fmaxf(a1[i][0] + b1v[i][0], 0.f));
            pk.y = pack_split(fmaxf(a1[i][1] + b1v[i][1], 0.f));
            pk.z = pack_split(fmaxf(a1[i][2] + b1v[i][2], 0.f));
            pk.w = pack_split(fmaxf(a1[i][3] + b1v[i][3], 0.f));
            *(uint4*)(d + 4 * i) = pk;
        }
    }
    __syncthreads();

    // ---- compute tile 1 ----------------------------------------------------
    gemm2_compute(sH[1], sRecv[1], w2hp, w2lp, b2, seg, w, quad, l16);
}

// ---------------------------------------------------------------------------
// tail_kernel: per node: m = seg/cnt ; out = relu(m @ Wd1 + bd1) @ Wd2 + bd2
// ---------------------------------------------------------------------------
__global__ __launch_bounds__(256) void tail_kernel(
    const float* __restrict__ seg, const uint32_t* __restrict__ row_off,
    const float* __restrict__ bd1, const float* __restrict__ Wd2,
    const float* __restrict__ bd2, float* __restrict__ out)
{
    __shared__ __align__(16) uint32_t sA[64 * 132];
    __shared__ float sOut[64];
    const int t = threadIdx.x;
    const int w = t >> 6, lane = t & 63, quad = lane >> 4, l16 = lane & 15;
    const int node0 = blockIdx.x * 64;

    if (t < 64) sOut[t] = 0.f;

    {
        const int r = t >> 2, kq = (t & 3) * 32;
        const int node = node0 + r;
        f32x4 v[8];
        if (node < NN) {
            uint32_t c = row_off[node + 1] - row_off[node];
            float inv = (c > 0u) ? 1.0f / (float)c : 0.f;
            const float* p = seg + (size_t)node * 128 + kq;
            #pragma unroll
            for (int i = 0; i < 8; ++i) v[i] = *(const f32x4*)(p + 4 * i) * inv;
        } else {
            #pragma unroll
            for (int i = 0; i < 8; ++i) v[i] = (f32x4){0.f, 0.f, 0.f, 0.f};
        }
        uint32_t* d = sA + r * 132 + kq;
        const int rot = t & 3;
        #pragma unroll
        for (int i = 0; i < 8; ++i) {
            const int ii = (i + rot) & 7;
            f32x4 vv = v[ii];
            uint4 pk;
            pk.x = pack_split(vv[0]); pk.y = pack_split(vv[1]);
            pk.z = pack_split(vv[2]); pk.w = pack_split(vv[3]);
            *(uint4*)(d + 4 * ii) = pk;
        }
    }
    __syncthreads();

    const int n = 16 * w + l16;
    const __bf16* bhp = g_wd1h + n * 128;
    const __bf16* blp = g_wd1l + n * 128;
    f32x4 acc[4] = {};
    #pragma unroll
    for (int kq = 0; kq < 4; ++kq) {
        const int k0 = kq * 32 + quad * 8;
        bf16x8 bh = *(const bf16x8*)(bhp + k0);
        bf16x8 bl = *(const bf16x8*)(blp + k0);
        #pragma unroll
        for (int st = 0; st < 4; ++st) {
            const uint32_t* ap = sA + (16 * st + l16) * 132 + k0;
            uint4 u0 = *(const uint4*)ap, u1 = *(const uint4*)(ap + 4);
            bf16x8 ah, al; unpack8(u0, u1, ah, al);
            acc[st] = __builtin_amdgcn_mfma_f32_16x16x32_bf16(ah, bh, acc[st], 0, 0, 0);
            acc[st] = __builtin_amdgcn_mfma_f32_16x16x32_bf16(al, bh, acc[st], 0, 0, 0);
            acc[st] = __builtin_amdgcn_mfma_f32_16x16x32_bf16(ah, bl, acc[st], 0, 0, 0);
        }
    }

    const float bd1v = bd1[n];
    const float wd2v = Wd2[n];
    #pragma unroll
    for (int st = 0; st < 4; ++st) {
        #pragma unroll
        for (int r = 0; r < 4; ++r) {
            float p = fmaxf(acc[st][r] + bd1v, 0.f) * wd2v;
            p += __shfl_xor(p, 1, 16);
            p += __shfl_xor(p, 2, 16);
            p += __shfl_xor(p, 4, 16);
            p += __shfl_xor(p, 8, 16);
            if (l16 == 0) atomicAdd(&sOut[16 * st + quad * 4 + r], p);
        }
    }
    __syncthreads();
    if (t < 64) {
        const int node = node0 + t;
        if (node < NN) out[node] = sOut[t] + bd2[0];
    }
}

// ---------------------------------------------------------------------------
extern "C" void kernel_launch(void* const* d_in, const int* in_sizes, int n_in,
                              void* d_out, int out_size, void* d_ws, size_t ws_size,
                              hipStream_t stream) {
    const float* x   = (const float*)d_in[0];
    const int*   snd = (const int*)  d_in[1];
    const int*   rcv = (const int*)  d_in[2];
    const float* W1a = (const float*)d_in[3];
    const float* b1a = (const float*)d_in[4];
    const float* W2a = (const float*)d_in[5];
    const float* b2a = (const float*)d_in[6];
    const float* W1b = (const float*)d_in[7];
    const float* b1b = (const float*)d_in[8];
    const float* W2b = (const float*)d_in[9];
    const float* b2b = (const float*)d_in[10];
    const float* Wd1 = (const float*)d_in[11];
    const float* bd1 = (const float*)d_in[12];
    const float* Wd2 = (const float*)d_in[13];
    const float* bd2 = (const float*)d_in[14];
    float* out = (float*)d_out;

    // ws layout: seg [NN*128 f32] | hist [NN] | cursor [NN] | row_off [NN+1] |
    //            pre [NN] | bsum [256] | srt [NE int2] | hrp [NN*64] | hsp [NN*64]
    float*    seg     = (float*)d_ws;
    uint32_t* hist    = (uint32_t*)(seg + (size_t)NN * 128);
    uint32_t* cursor  = hist + NN;
    uint32_t* row_off = cursor + NN;
    uint32_t* pre     = row_off + (NN + 1);
    uint32_t* bsum    = pre + NN;
    int2*     srt     = (int2*)(bsum + 256);
    float*    hrp     = (float*)(srt + NE);
    float*    hsp     = hrp + (size_t)NN * 64;

    hipMemsetAsync(seg, 0, ((size_t)NN * 128 + 2 * NN) * sizeof(float), stream);

    const int nb  = (NN + 255) / 256;   // 196
    const int nbn = (NN + 63) / 64;     // 782
    const int neb = (NE + 255) / 256;   // 3125

    hipLaunchKernelGGL(pre_kernel, dim3(224 + neb), dim3(256), 0, stream,
                       W1a, W2a, W1b, W2b, Wd1, rcv, hist);
    hipLaunchKernelGGL(scan1_kernel, dim3(nb), dim3(256), 0, stream, hist, pre, bsum);
    hipLaunchKernelGGL(scan2_kernel, dim3(1), dim3(256), 0, stream, bsum, nb);
    hipLaunchKernelGGL(scan3_kernel, dim3(nb), dim3(256), 0, stream, pre, bsum, row_off);
    hipLaunchKernelGGL(mid_kernel, dim3(nbn + neb), dim3(256), 0, stream,
                       x, b1a, hrp, hsp, rcv, snd, row_off, cursor, srt, nbn);

    // layer 1 edges
    hipLaunchKernelGGL(edge_gemm2_kernel, dim3(NE / 128), dim3(256), 0, stream,
                       hrp, hsp, srt, b2a, seg, 0);
    // layer 2 node half-products (mean-mode; rezeros seg)
    hipLaunchKernelGGL(node_w1_kernel, dim3(nbn), dim3(256), 0, stream,
                       seg, row_off, seg, b1b, hrp, hsp, 1);
    // layer 2 edges
    hipLaunchKernelGGL(edge_gemm2_kernel, dim3(NE / 128), dim3(256), 0, stream,
                       hrp, hsp, srt, b2b, seg, 1);
    // dense tail
    hipLaunchKernelGGL(tail_kernel, dim3(nbn), dim3(256), 0, stream,
                       seg, row_off, bd1, Wd2, bd2, out);
}

// Round 7
// 709.696 us; speedup vs baseline: 4.1419x; 1.0373x over previous
//
#include <hip/hip_runtime.h>
#include <hip/hip_bf16.h>
#include <cstdint>
#include <cstddef>

#define NN 50000
#define NE 800000

typedef __bf16 bf16x8 __attribute__((ext_vector_type(8)));
typedef float  f32x4  __attribute__((ext_vector_type(4)));

// Pre-split, pre-transposed weights.
// W1t hi/lo: [n][k] n<64,k<256 ; W2 packed u32 (hi|lo<<16): [n][k] n<128,k<64 ;
// Wd1t hi/lo: [n][k] n<64,k<128.
__device__ __bf16   g_w1h[2][64 * 256];
__device__ __bf16   g_w1l[2][64 * 256];
__device__ uint32_t g_w2p[2][128 * 64];
__device__ __bf16   g_wd1h[64 * 128];
__device__ __bf16   g_wd1l[64 * 128];

__device__ __forceinline__ void split1(float v, __bf16& h, __bf16& l) {
    h = (__bf16)v;
    l = (__bf16)(v - (float)h);
}

// pack: low16 = hi bf16 bits, high16 = lo bf16 bits
__device__ __forceinline__ uint32_t pack_split(float v) {
    __bf16 h, l; split1(v, h, l);
    return (uint32_t)__builtin_bit_cast(unsigned short, h)
         | ((uint32_t)__builtin_bit_cast(unsigned short, l) << 16);
}

// 8 packed u32 (k0..k0+7) -> hi-plane and lo-plane bf16x8 fragments
__device__ __forceinline__ void unpack8(uint4 u0, uint4 u1, bf16x8& ah, bf16x8& al) {
    const uint32_t a[8] = {u0.x, u0.y, u0.z, u0.w, u1.x, u1.y, u1.z, u1.w};
    union { uint32_t u[4]; bf16x8 v; } H, L;
    #pragma unroll
    for (int i = 0; i < 4; ++i) {
        H.u[i] = (a[2*i] & 0xffffu) | (a[2*i+1] << 16);
        L.u[i] = (a[2*i] >> 16)     | (a[2*i+1] & 0xffff0000u);
    }
    ah = H.v; al = L.v;
}

// ---------------------------------------------------------------------------
// pre_kernel: blocks [0,224) split weights; blocks [224,224+3125) histogram
// ---------------------------------------------------------------------------
__global__ __launch_bounds__(256) void pre_kernel(
    const float* __restrict__ W1a, const float* __restrict__ W2a,
    const float* __restrict__ W1b, const float* __restrict__ W2b,
    const float* __restrict__ Wd1,
    const int* __restrict__ rcv, uint32_t* __restrict__ hist)
{
    const int b = blockIdx.x, t = threadIdx.x;
    if (b < 224) {
        int tid = b * 256 + t;
        if (tid < 16384) {                 // W1a [256][64] -> [64][256]
            int k = tid >> 6, n = tid & 63;
            __bf16 h, l; split1(W1a[tid], h, l);
            g_w1h[0][n * 256 + k] = h; g_w1l[0][n * 256 + k] = l;
        } else if (tid < 24576) {          // W2a [64][128] -> packed [128][64]
            int i = tid - 16384; int k = i >> 7, n = i & 127;
            g_w2p[0][n * 64 + k] = pack_split(W2a[i]);
        } else if (tid < 40960) {          // W1b
            int i = tid - 24576; int k = i >> 6, n = i & 63;
            __bf16 h, l; split1(W1b[i], h, l);
            g_w1h[1][n * 256 + k] = h; g_w1l[1][n * 256 + k] = l;
        } else if (tid < 49152) {          // W2b
            int i = tid - 40960; int k = i >> 7, n = i & 127;
            g_w2p[1][n * 64 + k] = pack_split(W2b[i]);
        } else if (tid < 57344) {          // Wd1 [128][64] -> [64][128]
            int i = tid - 49152; int k = i >> 6, n = i & 63;
            __bf16 h, l; split1(Wd1[i], h, l);
            g_wd1h[n * 128 + k] = h; g_wd1l[n * 128 + k] = l;
        }
    } else {
        int e = (b - 224) * 256 + t;
        if (e < NE) atomicAdd(hist + rcv[e], 1u);
    }
}

// ---------------------------------------------------------------------------
// scan chain for counting sort
// ---------------------------------------------------------------------------
__global__ void scan1_kernel(const uint32_t* __restrict__ hist,
                             uint32_t* __restrict__ pre, uint32_t* __restrict__ bsum) {
    __shared__ uint32_t s[256];
    int t = threadIdx.x;
    int i = blockIdx.x * 256 + t;
    uint32_t v = (i < NN) ? hist[i] : 0u;
    s[t] = v; __syncthreads();
    #pragma unroll
    for (int off = 1; off < 256; off <<= 1) {
        uint32_t tv = (t >= off) ? s[t - off] : 0u;
        __syncthreads();
        s[t] += tv; __syncthreads();
    }
    if (i < NN) pre[i] = s[t] - v;
    if (t == 255) bsum[blockIdx.x] = s[255];
}

__global__ void scan2_kernel(uint32_t* __restrict__ bsum, int nb) {
    __shared__ uint32_t s[256];
    int t = threadIdx.x;
    uint32_t v = (t < nb) ? bsum[t] : 0u;
    s[t] = v; __syncthreads();
    #pragma unroll
    for (int off = 1; off < 256; off <<= 1) {
        uint32_t tv = (t >= off) ? s[t - off] : 0u;
        __syncthreads();
        s[t] += tv; __syncthreads();
    }
    if (t < nb) bsum[t] = s[t] - v;
}

__global__ void scan3_kernel(const uint32_t* __restrict__ pre,
                             const uint32_t* __restrict__ bsum,
                             uint32_t* __restrict__ row_off) {
    int i = blockIdx.x * 256 + threadIdx.x;
    if (i < NN) row_off[i] = pre[i] + bsum[blockIdx.x];
    if (i == 0) row_off[NN] = NE;
}

// ---------------------------------------------------------------------------
// node_w1_body: per-node half-products of GEMM1.
//   hrp[n] = src[n] @ W1_top + b1 ; hsp[n] = src[n] @ W1_bot
// mean-mode (row_off != null): scale by 1/cnt and rezero seg.
// ---------------------------------------------------------------------------
__device__ __forceinline__ void node_w1_body(
    const float* __restrict__ src, const uint32_t* __restrict__ row_off,
    float* __restrict__ seg_rz, const float* __restrict__ b1,
    float* __restrict__ hrp, float* __restrict__ hsp, int layer, int blk)
{
    __shared__ __align__(16) uint32_t sA[64 * 132];
    const int t = threadIdx.x;
    const int w = t >> 6, lane = t & 63, quad = lane >> 4, l16 = lane & 15;
    const int node0 = blk * 64;

    {
        const int r = t >> 2, kq = (t & 3) * 32;
        const int node = node0 + r;
        f32x4 v[8];
        if (node < NN) {
            const float* p = src + (size_t)node * 128 + kq;
            #pragma unroll
            for (int i = 0; i < 8; ++i) v[i] = *(const f32x4*)(p + 4 * i);
            if (row_off) {
                uint32_t c = row_off[node + 1] - row_off[node];
                float inv = (c > 0u) ? 1.0f / (float)c : 0.f;
                #pragma unroll
                for (int i = 0; i < 8; ++i) v[i] = v[i] * inv;
                float* z = seg_rz + (size_t)node * 128 + kq;
                #pragma unroll
                for (int i = 0; i < 8; ++i) *(f32x4*)(z + 4 * i) = (f32x4){0.f, 0.f, 0.f, 0.f};
            }
        } else {
            #pragma unroll
            for (int i = 0; i < 8; ++i) v[i] = (f32x4){0.f, 0.f, 0.f, 0.f};
        }
        uint32_t* d = sA + r * 132 + kq;
        const int rot = t & 3;
        #pragma unroll
        for (int i = 0; i < 8; ++i) {
            const int ii = (i + rot) & 7;
            f32x4 vv = v[ii];
            uint4 pk;
            pk.x = pack_split(vv[0]); pk.y = pack_split(vv[1]);
            pk.z = pack_split(vv[2]); pk.w = pack_split(vv[3]);
            *(uint4*)(d + 4 * ii) = pk;
        }
    }
    __syncthreads();

    const int n = 16 * w + l16;
    const __bf16* w1hp = g_w1h[layer] + n * 256;
    const __bf16* w1lp = g_w1l[layer] + n * 256;
    f32x4 acc[4][2] = {};
    #pragma unroll
    for (int kq = 0; kq < 4; ++kq) {
        const int k0 = kq * 32 + quad * 8;
        bf16x8 bh0 = *(const bf16x8*)(w1hp + k0);
        bf16x8 bl0 = *(const bf16x8*)(w1lp + k0);
        bf16x8 bh1 = *(const bf16x8*)(w1hp + 128 + k0);
        bf16x8 bl1 = *(const bf16x8*)(w1lp + 128 + k0);
        #pragma unroll
        for (int st = 0; st < 4; ++st) {
            const uint32_t* ap = sA + (16 * st + l16) * 132 + k0;
            uint4 u0 = *(const uint4*)ap, u1 = *(const uint4*)(ap + 4);
            bf16x8 ah, al; unpack8(u0, u1, ah, al);
            acc[st][0] = __builtin_amdgcn_mfma_f32_16x16x32_bf16(ah, bh0, acc[st][0], 0, 0, 0);
            acc[st][0] = __builtin_amdgcn_mfma_f32_16x16x32_bf16(al, bh0, acc[st][0], 0, 0, 0);
            acc[st][0] = __builtin_amdgcn_mfma_f32_16x16x32_bf16(ah, bl0, acc[st][0], 0, 0, 0);
            acc[st][1] = __builtin_amdgcn_mfma_f32_16x16x32_bf16(ah, bh1, acc[st][1], 0, 0, 0);
            acc[st][1] = __builtin_amdgcn_mfma_f32_16x16x32_bf16(al, bh1, acc[st][1], 0, 0, 0);
            acc[st][1] = __builtin_amdgcn_mfma_f32_16x16x32_bf16(ah, bl1, acc[st][1], 0, 0, 0);
        }
    }

    const float b1v = b1[n];
    #pragma unroll
    for (int st = 0; st < 4; ++st) {
        #pragma unroll
        for (int r = 0; r < 4; ++r) {
            const int node = node0 + 16 * st + quad * 4 + r;
            if (node < NN) {
                hrp[(size_t)node * 64 + n] = acc[st][0][r] + b1v;
                hsp[(size_t)node * 64 + n] = acc[st][1][r];
            }
        }
    }
}

// standalone node_w1 (layer-2 mean mode)
__global__ __launch_bounds__(256) void node_w1_kernel(
    const float* __restrict__ src, const uint32_t* __restrict__ row_off,
    float* __restrict__ seg_rz, const float* __restrict__ b1,
    float* __restrict__ hrp, float* __restrict__ hsp, int layer)
{
    node_w1_body(src, row_off, seg_rz, b1, hrp, hsp, layer, blockIdx.x);
}

// ---------------------------------------------------------------------------
// mid_kernel: blocks [0,nbn) = node_w1 layer-0; rest = rank-scatter building
// sorted (recv,send) pairs.
// ---------------------------------------------------------------------------
__global__ __launch_bounds__(256) void mid_kernel(
    const float* __restrict__ x, const float* __restrict__ b1a,
    float* __restrict__ hrp, float* __restrict__ hsp,
    const int* __restrict__ rcv, const int* __restrict__ snd,
    const uint32_t* __restrict__ row_off, uint32_t* __restrict__ cursor,
    int2* __restrict__ srt, int nbn)
{
    if ((int)blockIdx.x < nbn) {
        node_w1_body(x, (const uint32_t*)nullptr, (float*)nullptr, b1a, hrp, hsp, 0,
                     blockIdx.x);
    } else {
        int e = (blockIdx.x - nbn) * 256 + threadIdx.x;
        if (e < NE) {
            int r = rcv[e];
            uint32_t k = atomicAdd(cursor + r, 1u);
            srt[row_off[r] + k] = make_int2(r, snd[e]);
        }
    }
}

// ---------------------------------------------------------------------------
// edge_gemm2_kernel: 64 sorted edges/block, 4 waves; wave w owns edges
// e0+16w..e0+16w+16 and ALL 128 output cols. A-fragments built per-lane in
// registers straight from the hrp/hsp gathers (A-layout = 8 contiguous k).
// Pre-packed W2 staged once in LDS; single __syncthreads, then free-run.
// ---------------------------------------------------------------------------
__global__ __launch_bounds__(256) void edge_gemm2_kernel(
    const float* __restrict__ hrp, const float* __restrict__ hsp,
    const int2* __restrict__ srt,
    const float* __restrict__ b2,
    float* __restrict__ seg, int layer)
{
    __shared__ __align__(16) uint32_t sW[128 * 68];   // packed W2, row stride 68

    const int t = threadIdx.x;
    const int w = t >> 6, lane = t & 63, quad = lane >> 4, l16 = lane & 15;

    // ---- stage packed W2 (32 KB copy; thread t -> row t>>1, half (t&1)) ----
    {
        const int r = t >> 1, k0s = (t & 1) * 32;
        const uint32_t* src = g_w2p[layer] + r * 64 + k0s;
        uint32_t* dst = sW + r * 68 + k0s;
        #pragma unroll
        for (int i = 0; i < 8; ++i)
            *(uint4*)(dst + 4 * i) = *(const uint4*)(src + 4 * i);
    }

    // ---- gather this wave's 16 edges (independent, overlap staging) --------
    const int e0 = blockIdx.x * 64 + w * 16;
    const int2 rs = srt[e0 + l16];          // all 4 quads: same edge per l16
    const int koff = quad * 8;
    const float* hp = hrp + (size_t)rs.x * 64 + koff;
    const float* sp = hsp + (size_t)rs.y * 64 + koff;
    f32x4 ga[4], gb[4];                     // [s*2+half] : k = s*32+quad*8+half*4
    ga[0] = *(const f32x4*)(hp);      ga[1] = *(const f32x4*)(hp + 4);
    ga[2] = *(const f32x4*)(hp + 32); ga[3] = *(const f32x4*)(hp + 36);
    gb[0] = *(const f32x4*)(sp);      gb[1] = *(const f32x4*)(sp + 4);
    gb[2] = *(const f32x4*)(sp + 32); gb[3] = *(const f32x4*)(sp + 36);

    float b2v[8];
    #pragma unroll
    for (int ct = 0; ct < 8; ++ct) b2v[ct] = b2[16 * ct + l16];

    // ---- A-fragments in registers: h = relu(hrp+hsp), split hi/lo ----------
    bf16x8 ah[2], al[2];
    #pragma unroll
    for (int s = 0; s < 2; ++s) {
        #pragma unroll
        for (int hh = 0; hh < 2; ++hh) {
            f32x4 av = ga[s * 2 + hh], bv = gb[s * 2 + hh];
            #pragma unroll
            for (int j = 0; j < 4; ++j) {
                float v = fmaxf(av[j] + bv[j], 0.f);
                __bf16 h, l; split1(v, h, l);
                ah[s][hh * 4 + j] = h;
                al[s][hh * 4 + j] = l;
            }
        }
    }

    // receivers for epilogue rows (edge l16 held by lane l16 of each quad-group)
    const int recvA  = rs.x;
    const int rcHead = __shfl(recvA, 0, 16);
    const int rcTail = __shfl(recvA, 15, 16);
    int rc[4];
    #pragma unroll
    for (int r = 0; r < 4; ++r) rc[r] = __shfl(recvA, quad * 4 + r, 16);

    __syncthreads();   // weights staged

    // ---- GEMM2: 8 col-tiles x 2 k-steps x 3 split-mfma ---------------------
    f32x4 acc[8] = {};
    #pragma unroll
    for (int ct = 0; ct < 8; ++ct) {
        #pragma unroll
        for (int s = 0; s < 2; ++s) {
            const uint32_t* bp = sW + (16 * ct + l16) * 68 + s * 32 + quad * 8;
            uint4 u0 = *(const uint4*)bp, u1 = *(const uint4*)(bp + 4);
            bf16x8 bh, bl; unpack8(u0, u1, bh, bl);
            acc[ct] = __builtin_amdgcn_mfma_f32_16x16x32_bf16(ah[s], bh, acc[ct], 0, 0, 0);
            acc[ct] = __builtin_amdgcn_mfma_f32_16x16x32_bf16(al[s], bh, acc[ct], 0, 0, 0);
            acc[ct] = __builtin_amdgcn_mfma_f32_16x16x32_bf16(ah[s], bl, acc[ct], 0, 0, 0);
        }
    }

    // ---- epilogue: relu(+b2); strip-uniform fast path / quad run-reduce ----
    const bool uniform = (rcHead == rcTail);
    #pragma unroll
    for (int ct = 0; ct < 8; ++ct) {
        const int n = 16 * ct + l16;
        float v[4];
        #pragma unroll
        for (int r = 0; r < 4; ++r)
            v[r] = fmaxf(acc[ct][r] + b2v[ct], 0.f);
        if (uniform) {
            float sm = (v[0] + v[1]) + (v[2] + v[3]);
            sm += __shfl_xor(sm, 16);
            sm += __shfl_xor(sm, 32);
            if (quad == 0) atomicAdd(seg + (size_t)rcHead * 128 + n, sm);
        } else {
            int prev = rc[0];
            float sm = v[0];
            #pragma unroll
            for (int r = 1; r < 4; ++r) {
                if (rc[r] == prev) {
                    sm += v[r];
                } else {
                    atomicAdd(seg + (size_t)prev * 128 + n, sm);
                    prev = rc[r];
                    sm = v[r];
                }
            }
            atomicAdd(seg + (size_t)prev * 128 + n, sm);
        }
    }
}

// ---------------------------------------------------------------------------
// tail_kernel: per node: m = seg/cnt ; out = relu(m @ Wd1 + bd1) @ Wd2 + bd2
// ---------------------------------------------------------------------------
__global__ __launch_bounds__(256) void tail_kernel(
    const float* __restrict__ seg, const uint32_t* __restrict__ row_off,
    const float* __restrict__ bd1, const float* __restrict__ Wd2,
    const float* __restrict__ bd2, float* __restrict__ out)
{
    __shared__ __align__(16) uint32_t sA[64 * 132];
    __shared__ float sOut[64];
    const int t = threadIdx.x;
    const int w = t >> 6, lane = t & 63, quad = lane >> 4, l16 = lane & 15;
    const int node0 = blockIdx.x * 64;

    if (t < 64) sOut[t] = 0.f;

    {
        const int r = t >> 2, kq = (t & 3) * 32;
        const int node = node0 + r;
        f32x4 v[8];
        if (node < NN) {
            uint32_t c = row_off[node + 1] - row_off[node];
            float inv = (c > 0u) ? 1.0f / (float)c : 0.f;
            const float* p = seg + (size_t)node * 128 + kq;
            #pragma unroll
            for (int i = 0; i < 8; ++i) v[i] = *(const f32x4*)(p + 4 * i) * inv;
        } else {
            #pragma unroll
            for (int i = 0; i < 8; ++i) v[i] = (f32x4){0.f, 0.f, 0.f, 0.f};
        }
        uint32_t* d = sA + r * 132 + kq;
        const int rot = t & 3;
        #pragma unroll
        for (int i = 0; i < 8; ++i) {
            const int ii = (i + rot) & 7;
            f32x4 vv = v[ii];
            uint4 pk;
            pk.x = pack_split(vv[0]); pk.y = pack_split(vv[1]);
            pk.z = pack_split(vv[2]); pk.w = pack_split(vv[3]);
            *(uint4*)(d + 4 * ii) = pk;
        }
    }
    __syncthreads();

    const int n = 16 * w + l16;
    const __bf16* bhp = g_wd1h + n * 128;
    const __bf16* blp = g_wd1l + n * 128;
    f32x4 acc[4] = {};
    #pragma unroll
    for (int kq = 0; kq < 4; ++kq) {
        const int k0 = kq * 32 + quad * 8;
        bf16x8 bh = *(const bf16x8*)(bhp + k0);
        bf16x8 bl = *(const bf16x8*)(blp + k0);
        #pragma unroll
        for (int st = 0; st < 4; ++st) {
            const uint32_t* ap = sA + (16 * st + l16) * 132 + k0;
            uint4 u0 = *(const uint4*)ap, u1 = *(const uint4*)(ap + 4);
            bf16x8 ah, al; unpack8(u0, u1, ah, al);
            acc[st] = __builtin_amdgcn_mfma_f32_16x16x32_bf16(ah, bh, acc[st], 0, 0, 0);
            acc[st] = __builtin_amdgcn_mfma_f32_16x16x32_bf16(al, bh, acc[st], 0, 0, 0);
            acc[st] = __builtin_amdgcn_mfma_f32_16x16x32_bf16(ah, bl, acc[st], 0, 0, 0);
        }
    }

    const float bd1v = bd1[n];
    const float wd2v = Wd2[n];
    #pragma unroll
    for (int st = 0; st < 4; ++st) {
        #pragma unroll
        for (int r = 0; r < 4; ++r) {
            float p = fmaxf(acc[st][r] + bd1v, 0.f) * wd2v;
            p += __shfl_xor(p, 1, 16);
            p += __shfl_xor(p, 2, 16);
            p += __shfl_xor(p, 4, 16);
            p += __shfl_xor(p, 8, 16);
            if (l16 == 0) atomicAdd(&sOut[16 * st + quad * 4 + r], p);
        }
    }
    __syncthreads();
    if (t < 64) {
        const int node = node0 + t;
        if (node < NN) out[node] = sOut[t] + bd2[0];
    }
}

// ---------------------------------------------------------------------------
extern "C" void kernel_launch(void* const* d_in, const int* in_sizes, int n_in,
                              void* d_out, int out_size, void* d_ws, size_t ws_size,
                              hipStream_t stream) {
    const float* x   = (const float*)d_in[0];
    const int*   snd = (const int*)  d_in[1];
    const int*   rcv = (const int*)  d_in[2];
    const float* W1a = (const float*)d_in[3];
    const float* b1a = (const float*)d_in[4];
    const float* W2a = (const float*)d_in[5];
    const float* b2a = (const float*)d_in[6];
    const float* W1b = (const float*)d_in[7];
    const float* b1b = (const float*)d_in[8];
    const float* W2b = (const float*)d_in[9];
    const float* b2b = (const float*)d_in[10];
    const float* Wd1 = (const float*)d_in[11];
    const float* bd1 = (const float*)d_in[12];
    const float* Wd2 = (const float*)d_in[13];
    const float* bd2 = (const float*)d_in[14];
    float* out = (float*)d_out;

    // ws layout: seg [NN*128 f32] | hist [NN] | cursor [NN] | row_off [NN+1] |
    //            pre [NN] | bsum [256] | srt [NE int2] | hrp [NN*64] | hsp [NN*64]
    float*    seg     = (float*)d_ws;
    uint32_t* hist    = (uint32_t*)(seg + (size_t)NN * 128);
    uint32_t* cursor  = hist + NN;
    uint32_t* row_off = cursor + NN;
    uint32_t* pre     = row_off + (NN + 1);
    uint32_t* bsum    = pre + NN;
    int2*     srt     = (int2*)(bsum + 256);
    float*    hrp     = (float*)(srt + NE);
    float*    hsp     = hrp + (size_t)NN * 64;

    hipMemsetAsync(seg, 0, ((size_t)NN * 128 + 2 * NN) * sizeof(float), stream);

    const int nb  = (NN + 255) / 256;   // 196
    const int nbn = (NN + 63) / 64;     // 782
    const int neb = (NE + 255) / 256;   // 3125

    hipLaunchKernelGGL(pre_kernel, dim3(224 + neb), dim3(256), 0, stream,
                       W1a, W2a, W1b, W2b, Wd1, rcv, hist);
    hipLaunchKernelGGL(scan1_kernel, dim3(nb), dim3(256), 0, stream, hist, pre, bsum);
    hipLaunchKernelGGL(scan2_kernel, dim3(1), dim3(256), 0, stream, bsum, nb);
    hipLaunchKernelGGL(scan3_kernel, dim3(nb), dim3(256), 0, stream, pre, bsum, row_off);
    hipLaunchKernelGGL(mid_kernel, dim3(nbn + neb), dim3(256), 0, stream,
                       x, b1a, hrp, hsp, rcv, snd, row_off, cursor, srt, nbn);

    // layer 1 edges
    hipLaunchKernelGGL(edge_gemm2_kernel, dim3(NE / 64), dim3(256), 0, stream,
                       hrp, hsp, srt, b2a, seg, 0);
    // layer 2 node half-products (mean-mode; rezeros seg)
    hipLaunchKernelGGL(node_w1_kernel, dim3(nbn), dim3(256), 0, stream,
                       seg, row_off, seg, b1b, hrp, hsp, 1);
    // layer 2 edges
    hipLaunchKernelGGL(edge_gemm2_kernel, dim3(NE / 64), dim3(256), 0, stream,
                       hrp, hsp, srt, b2b, seg, 1);
    // dense tail
    hipLaunchKernelGGL(tail_kernel, dim3(nbn), dim3(256), 0, stream,
                       seg, row_off, bd1, Wd2, bd2, out);
}